// Round 11
// baseline (10400.174 us; speedup 1.0000x reference)
//
#include <hip/hip_runtime.h>
#include <math.h>
#include <stdint.h>

__device__ __align__(256) char g_scratch[234881024];  // 224 MB

#define NBR_CAP 2048

// ---------------- sq: per-row sum of squares (f64 + f32, for dist-GEMM window only) ----------------
__global__ __launch_bounds__(256) void sq_kernel(const float* __restrict__ x,
                                                 double* __restrict__ sq64,
                                                 float* __restrict__ sqf){
  int wid = threadIdx.x >> 6, lane = threadIdx.x & 63;
  int row = blockIdx.x*4 + wid;
  const float* xr = x + (size_t)row*1024;
  double acc = 0.0;
  for (int k = lane; k < 1024; k += 64){ float v = xr[k]; acc += (double)v*(double)v; }
  for (int o = 32; o > 0; o >>= 1) acc += __shfl_down(acc, o);
  if (lane == 0){ sq64[row] = acc; sqf[row] = (float)acc; }
}

// ---------------- f32 LDS-tiled GEMM, 64x64 tile ----------------
// EPI: 0=none 1=tanh 2=sigmoid 3=dist(sq_i+sq_j-2c)
template<bool TRANSB, int EPI>
__global__ __launch_bounds__(256) void sgemm_k(
    const float* __restrict__ A, const float* __restrict__ B,
    const float* __restrict__ bias, const float* __restrict__ sqf,
    float* __restrict__ C, int M, int N, int K)
{
  __shared__ float As[64][17];
  __shared__ float Bs[16][65];
  const int tid = threadIdx.x;
  const int tx = tid & 15, ty = tid >> 4;
  const int rowBase = blockIdx.y*64, colBase = blockIdx.x*64;
  float acc[4][4] = {{0.f}};

  for (int k0 = 0; k0 < K; k0 += 16){
    #pragma unroll
    for (int p = 0; p < 4; ++p){
      int idx = p*256 + tid;
      int r = idx >> 4, kk = idx & 15;
      int gk = k0 + kk;
      As[r][kk] = (gk < K) ? A[(size_t)(rowBase+r)*K + gk] : 0.f;
    }
    if (!TRANSB){
      #pragma unroll
      for (int p = 0; p < 4; ++p){
        int idx = p*256 + tid;
        int k = idx >> 6, c = idx & 63;
        int gk = k0 + k, gc = colBase + c;
        Bs[k][c] = (gk < K && gc < N) ? B[(size_t)gk*N + gc] : 0.f;
      }
    } else {
      #pragma unroll
      for (int p = 0; p < 4; ++p){
        int idx = p*256 + tid;
        int k = idx & 15, c = idx >> 4;
        int gk = k0 + k, gc = colBase + c;
        Bs[k][c] = (gk < K && gc < N) ? B[(size_t)gc*K + gk] : 0.f;
      }
    }
    __syncthreads();
    #pragma unroll
    for (int k = 0; k < 16; ++k){
      float a[4], b[4];
      #pragma unroll
      for (int i=0;i<4;++i) a[i] = As[ty*4+i][k];
      #pragma unroll
      for (int j=0;j<4;++j) b[j] = Bs[k][tx*4+j];
      #pragma unroll
      for (int i=0;i<4;++i)
        #pragma unroll
        for (int j=0;j<4;++j) acc[i][j] = fmaf(a[i], b[j], acc[i][j]);
    }
    __syncthreads();
  }

  #pragma unroll
  for (int i=0;i<4;++i){
    int row = rowBase + ty*4 + i;
    #pragma unroll
    for (int j=0;j<4;++j){
      int col = colBase + tx*4 + j;
      if (col < N){
        float c = acc[i][j];
        if (EPI == 3) c = sqf[row] + sqf[col] - 2.0f*c;
        if (bias) c += bias[col];
        if (EPI == 1) c = tanhf(c);
        if (EPI == 2) c = 1.0f/(1.0f + expf(-c));
        C[(size_t)row*N + col] = c;
      }
    }
  }
}

// ---------------- kNN: f32 top-10 window + margin candidates (cap 96) ----------------
__global__ __launch_bounds__(256) void knn_select(const float* __restrict__ dists,
                                                  int* __restrict__ cand, int* __restrict__ candc){
  const int row = blockIdx.x, tid = threadIdx.x;
  __shared__ float drow[4096];
  __shared__ float rv[256]; __shared__ int ri[256];
  __shared__ float d10s;
  const float* dr = dists + (size_t)row*4096;
  for (int j = tid; j < 4096; j += 256) drow[j] = dr[j];
  __syncthreads();
  for (int t = 0; t < 10; ++t){
    float bv = 3.4e38f; int bi = 0x7FFFFFFF;
    for (int j = tid; j < 4096; j += 256){
      float v = drow[j];
      if (v < bv || (v == bv && j < bi)){ bv = v; bi = j; }
    }
    rv[tid] = bv; ri[tid] = bi;
    __syncthreads();
    for (int s = 128; s > 0; s >>= 1){
      if (tid < s){
        float ov = rv[tid+s]; int oi = ri[tid+s];
        if (ov < rv[tid] || (ov == rv[tid] && oi < ri[tid])){ rv[tid] = ov; ri[tid] = oi; }
      }
      __syncthreads();
    }
    if (tid == 0){ drow[ri[0]] = 3.4e38f; if (t == 9) d10s = rv[0]; }
    __syncthreads();
  }
  const float thr = d10s + 2.0f;
  if (tid < 64){
    int lane = tid;
    int cnt = 0;
    for (int base = 0; base < 4096; base += 64){
      bool p = dr[base+lane] <= thr;
      unsigned long long mask = __ballot(p);
      if (p){
        int pos = __popcll(mask & ((1ull<<lane)-1ull));
        if (cnt + pos < 96) cand[(size_t)row*96 + cnt + pos] = base + lane;
      }
      cnt += __popcll(mask);
    }
    if (lane == 0) candc[row] = cnt < 96 ? cnt : 96;
  }
}

// ---------------- kNN: f32-MIMIC re-rank of candidates ----------------
// Mimics a blocked BLAS f32 computation: 64 lane-strided FMA accumulators
// (k = lane + 64*t), pairwise lane-tree reduction (16,32 then 8,4,2,1),
// assembly (sq_i - 2*dot) + sq_j in f32 — numpy's expression order.
__global__ __launch_bounds__(256) void knn_rank32(const float* __restrict__ x,
    const int* __restrict__ cand, const int* __restrict__ candc,
    int* __restrict__ nbrK, int* __restrict__ nbrKc)
{
  const int row = blockIdx.x, tid = threadIdx.x;
  const int wid = tid>>6, lane = tid&63;
  __shared__ float xi[1024];
  __shared__ float cd[96];
  __shared__ float sqi_sh;
  const float* xr = x + (size_t)row*1024;
  for (int k = tid; k < 1024; k += 256) xi[k] = xr[k];
  __syncthreads();
  if (wid == 0){
    float a = 0.f;
    #pragma unroll
    for (int t = 0; t < 16; ++t){ float v = xi[lane + 64*t]; a = fmaf(v, v, a); }
    a += __shfl_xor(a, 16); a += __shfl_xor(a, 32);
    a += __shfl_xor(a, 8);  a += __shfl_xor(a, 4);
    a += __shfl_xor(a, 2);  a += __shfl_xor(a, 1);
    if (lane == 0) sqi_sh = a;
  }
  __syncthreads();
  const float sqi = sqi_sh;
  const int cnt = candc[row];
  for (int s = wid; s < cnt; s += 4){
    int c = cand[(size_t)row*96 + s];
    const float* xc = x + (size_t)c*1024;
    float ad = 0.f, aq = 0.f;
    #pragma unroll
    for (int t = 0; t < 16; ++t){
      int k = lane + 64*t;
      float v = xc[k];
      ad = fmaf(xi[k], v, ad);
      aq = fmaf(v, v, aq);
    }
    ad += __shfl_xor(ad, 16); ad += __shfl_xor(ad, 32);
    ad += __shfl_xor(ad, 8);  ad += __shfl_xor(ad, 4);
    ad += __shfl_xor(ad, 2);  ad += __shfl_xor(ad, 1);
    aq += __shfl_xor(aq, 16); aq += __shfl_xor(aq, 32);
    aq += __shfl_xor(aq, 8);  aq += __shfl_xor(aq, 4);
    aq += __shfl_xor(aq, 2);  aq += __shfl_xor(aq, 1);
    if (lane == 0) cd[s] = (sqi - 2.0f*ad) + aq;
  }
  __syncthreads();
  if (tid == 0){
    int m = 0;
    int lim = cnt < 10 ? cnt : 10;
    for (int t = 0; t < lim; ++t){
      float bd = 3.4e38f; int bs = 0;
      for (int s = 0; s < cnt; ++s){
        if (cd[s] < bd){ bd = cd[s]; bs = s; }   // ties -> lowest index (cand ascending)
      }
      cd[bs] = 3.4e38f;
      int j = cand[(size_t)row*96 + bs];
      if (j != row && m < 10){ nbrK[row*10 + m] = j; ++m; }
    }
    nbrKc[row] = m;
  }
}

__global__ __launch_bounds__(64) void scatter_k(const int* __restrict__ nbrK, const int* __restrict__ nbrKc,
                                                float* __restrict__ g){
  int row = blockIdx.x, t = threadIdx.x;
  int m = nbrKc[row];
  if (t < m){
    int j = nbrK[row*10 + t];
    g[(size_t)row*4096 + j] = 1.0f;
    g[(size_t)j*4096 + row] = 1.0f;
  }
}

__global__ __launch_bounds__(64) void build_lists(const float* __restrict__ g, int* __restrict__ nbrl,
                                                  int* __restrict__ nbrc, float* __restrict__ dinv){
  int row = blockIdx.x, lane = threadIdx.x;
  const float* gr = g + (size_t)row*4096;
  int cnt = 0;
  for (int base = 0; base < 4096; base += 64){
    bool p = gr[base+lane] != 0.f;
    unsigned long long mask = __ballot(p);
    if (p){
      int pos = __popcll(mask & ((1ull<<lane)-1ull));
      if (cnt + pos < NBR_CAP) nbrl[(size_t)row*NBR_CAP + cnt + pos] = base + lane;
    }
    cnt += __popcll(mask);
  }
  if (lane == 0){
    nbrc[row] = cnt < NBR_CAP ? cnt : NBR_CAP;
    dinv[row] = 1.0f/sqrtf((float)(cnt + 1));
  }
}

// ---------------- SpMM: out = s @ X ----------------
__global__ __launch_bounds__(256) void spmm_k(const float* __restrict__ X, const int* __restrict__ nbrl,
    const int* __restrict__ nbrc, const float* __restrict__ dinv, float* __restrict__ out, int W){
  const int row = blockIdx.x, tid = threadIdx.x;
  __shared__ int li[NBR_CAP]; __shared__ float lv[NBR_CAP];
  const int cnt = nbrc[row];
  const float di = dinv[row];
  for (int t = tid; t < cnt; t += 256){ int j = nbrl[(size_t)row*NBR_CAP + t]; li[t] = j; lv[t] = dinv[j]; }
  __syncthreads();
  for (int c = tid; c < W; c += 256){
    float acc = di * X[(size_t)row*W + c];
    for (int s = 0; s < cnt; ++s){
      int j = li[s];
      acc += lv[s]*X[(size_t)j*W + c];
    }
    out[(size_t)row*W + c] = di*acc;
  }
}

// ---------------- q = softmax(z @ lc_w + lc_b) ----------------
__global__ __launch_bounds__(64) void q_kernel(const float* __restrict__ z, const float* __restrict__ lcw,
                                               const float* __restrict__ lcb, float* __restrict__ qs){
  int row = blockIdx.x, lane = threadIdx.x;
  __shared__ float ls[10];
  const float* zr = z + (size_t)row*512;
  for (int c = 0; c < 10; ++c){
    float a = 0.f;
    for (int k = lane; k < 512; k += 64) a += zr[k]*lcw[k*10 + c];
    for (int o = 32; o > 0; o >>= 1) a += __shfl_down(a, o);
    if (lane == 0) ls[c] = a + lcb[c];
  }
  __syncthreads();
  if (lane == 0){
    float m = ls[0];
    for (int c = 1; c < 10; ++c) m = fmaxf(m, ls[c]);
    float sum = 0.f, e[10];
    for (int c = 0; c < 10; ++c){ e[c] = expf(ls[c]-m); sum += e[c]; }
    for (int c = 0; c < 10; ++c) qs[(size_t)row*10 + c] = e[c]/sum;
  }
}

// ---------------- h row-normalize ----------------
__global__ __launch_bounds__(64) void hnorm_k(const float* __restrict__ hp, float* __restrict__ hs){
  int row = blockIdx.x, lane = threadIdx.x;
  const float* hr = hp + (size_t)row*128;
  float v0 = hr[lane], v1 = hr[lane+64];
  float a = v0*v0 + v1*v1;
  for (int o = 32; o > 0; o >>= 1) a += __shfl_down(a, o);
  float nrm = sqrtf(__shfl(a, 0));
  hs[(size_t)row*128 + lane]      = v0/nrm;
  hs[(size_t)row*128 + lane + 64] = v1/nrm;
}

extern "C" void kernel_launch(void* const* d_in, const int* in_sizes, int n_in,
                              void* d_out, int out_size, void* d_ws, size_t ws_size,
                              hipStream_t stream)
{
  const float* xs  = (const float*)d_in[0];
  const float* ew1 = (const float*)d_in[1];
  const float* eb1 = (const float*)d_in[2];
  const float* ew2 = (const float*)d_in[3];
  const float* eb2 = (const float*)d_in[4];
  const float* eWp = (const float*)d_in[5];
  const float* dW1 = (const float*)d_in[6];
  const float* dw1 = (const float*)d_in[7];
  const float* db1 = (const float*)d_in[8];
  const float* dw2 = (const float*)d_in[9];
  const float* db2 = (const float*)d_in[10];
  const float* fcw = (const float*)d_in[11];
  const float* fcb = (const float*)d_in[12];
  const float* lcw = (const float*)d_in[13];
  const float* lcb = (const float*)d_in[14];

  float* out = (float*)d_out;   // OUTPUT IS FLOAT32
  const size_t HS0 = 0;
  const size_t QS0 = HS0 + (size_t)2*4096*128;
  const size_t XR0 = QS0 + (size_t)2*4096*10;
  const size_t ZS0 = XR0 + (size_t)2*4096*1024;
  const size_t GS0 = ZS0 + (size_t)2*4096*512;
  const size_t AR0 = GS0 + (size_t)2*4096*4096;

  void* sp = nullptr;
  hipGetSymbolAddress(&sp, HIP_SYMBOL(g_scratch));
  if (!sp) return;
  char* ws = (char*)sp;

  float* dists = (float*)(ws + 0);            // 64MB
  float* o1    = (float*)(ws + 67108864);     // 29.5MB (h11 aliases)
  float* so1   = (float*)(ws + 96600064);     // 29.5MB (sh11 aliases)
  float* sx    = (float*)(ws + 126091264);    // 16MB
  float* sh1   = (float*)(ws + 142868480);    // 8MB
  float* zw    = (float*)(ws + 151257088);    // 8MB
  float* h1    = (float*)(ws + 159645696);    // 8MB
  float* hpre  = (float*)(ws + 168034304);    // 2MB
  double* sq64 = (double*)(ws + 170131456);
  float* sqf   = (float*)(ws + 170164224);
  int* cand    = (int*)(ws + 170180608);      // 4096*96*4
  int* candc   = (int*)(ws + 171753472);
  int* nbrK    = (int*)(ws + 171769856);
  int* nbrKc   = (int*)(ws + 171933696);
  int* nbrl    = (int*)(ws + 171950080);      // 32MB
  int* nbrc    = (int*)(ws + 205504512);
  float* dinv  = (float*)(ws + 205520896);
  float* h11   = o1;
  float* sh11  = so1;

  hipMemsetAsync(out + GS0, 0, (size_t)2*4096*4096*sizeof(float), stream);

  for (int v = 0; v < 2; ++v){
    const float* x    = xs  + (size_t)v*4096*1024;
    const float* w1   = ew1 + (size_t)v*1024*1800;
    const float* b1   = eb1 + (size_t)v*1800;
    const float* w2   = ew2 + (size_t)v*1800*512;
    const float* b2   = eb2 + (size_t)v*512;
    const float* We   = eWp + (size_t)v*512*512;
    const float* dWv  = dW1 + (size_t)v*512*512;
    const float* dw1v = dw1 + (size_t)v*512*1800;
    const float* db1v = db1 + (size_t)v*1800;
    const float* dw2v = dw2 + (size_t)v*1800*1024;
    const float* db2v = db2 + (size_t)v*1024;
    float* hs_o = out + HS0 + (size_t)v*4096*128;
    float* qs_o = out + QS0 + (size_t)v*4096*10;
    float* xr_o = out + XR0 + (size_t)v*4096*1024;
    float* zs_o = out + ZS0 + (size_t)v*4096*512;
    float* gs_o = out + GS0 + (size_t)v*4096*4096;
    float* ar_o = out + AR0 + (size_t)v*4096*4096;

    // ---- graph ----
    sq_kernel<<<1024,256,0,stream>>>(x, sq64, sqf);
    sgemm_k<true,3><<<dim3(64,64),256,0,stream>>>(x,x,nullptr,sqf,dists,4096,4096,1024);
    knn_select<<<4096,256,0,stream>>>(dists, cand, candc);
    knn_rank32<<<4096,256,0,stream>>>(x, cand, candc, nbrK, nbrKc);
    scatter_k<<<4096,64,0,stream>>>(nbrK, nbrKc, gs_o);
    build_lists<<<4096,64,0,stream>>>(gs_o, nbrl, nbrc, dinv);

    // ---- encoder ----
    spmm_k<<<4096,256,0,stream>>>(x, nbrl, nbrc, dinv, sx, 1024);
    sgemm_k<false,1><<<dim3(29,64),256,0,stream>>>(sx,w1,b1,nullptr,o1,4096,1800,1024);
    spmm_k<<<4096,256,0,stream>>>(o1, nbrl, nbrc, dinv, so1, 1800);
    sgemm_k<false,1><<<dim3(8,64),256,0,stream>>>(so1,w2,b2,nullptr,zs_o,4096,512,1800);

    // ---- a = sigmoid((z@eW)@z^T) ----
    sgemm_k<false,0><<<dim3(8,64),256,0,stream>>>(zs_o,We,nullptr,nullptr,zw,4096,512,512);
    sgemm_k<true,2><<<dim3(64,64),256,0,stream>>>(zw,zs_o,nullptr,nullptr,ar_o,4096,4096,512);

    // ---- heads ----
    sgemm_k<false,0><<<dim3(2,64),256,0,stream>>>(zs_o,fcw,fcb,nullptr,hpre,4096,128,512);
    hnorm_k<<<4096,64,0,stream>>>(hpre, hs_o);
    q_kernel<<<4096,64,0,stream>>>(zs_o, lcw, lcb, qs_o);

    // ---- decoder ----
    sgemm_k<false,1><<<dim3(8,64),256,0,stream>>>(zs_o,dWv,nullptr,nullptr,h1,4096,512,512);
    spmm_k<<<4096,256,0,stream>>>(h1, nbrl, nbrc, dinv, sh1, 512);
    sgemm_k<false,1><<<dim3(29,64),256,0,stream>>>(sh1,dw1v,db1v,nullptr,h11,4096,1800,512);
    spmm_k<<<4096,256,0,stream>>>(h11, nbrl, nbrc, dinv, sh11, 1800);
    sgemm_k<false,1><<<dim3(16,64),256,0,stream>>>(sh11,dw2v,db2v,nullptr,xr_o,4096,1024,1800);
  }
}

// Round 12
// 7001.386 us; speedup vs baseline: 1.4854x; 1.4854x over previous
//
#include <hip/hip_runtime.h>
#include <math.h>
#include <stdint.h>

__device__ __align__(256) char g_scratch[234881024];  // 224 MB

#define NBR_CAP 2048

// ---------------- sq: per-row sum of squares (f64 + f32, for dist-GEMM window only) ----------------
__global__ __launch_bounds__(256) void sq_kernel(const float* __restrict__ x,
                                                 double* __restrict__ sq64,
                                                 float* __restrict__ sqf){
  int wid = threadIdx.x >> 6, lane = threadIdx.x & 63;
  int row = blockIdx.x*4 + wid;
  const float* xr = x + (size_t)row*1024;
  double acc = 0.0;
  for (int k = lane; k < 1024; k += 64){ float v = xr[k]; acc += (double)v*(double)v; }
  for (int o = 32; o > 0; o >>= 1) acc += __shfl_down(acc, o);
  if (lane == 0){ sq64[row] = acc; sqf[row] = (float)acc; }
}

// ---------------- f32 LDS-tiled GEMM, 64x64 tile ----------------
// EPI: 0=none 1=tanh 2=sigmoid 3=dist(sq_i+sq_j-2c)
template<bool TRANSB, int EPI>
__global__ __launch_bounds__(256) void sgemm_k(
    const float* __restrict__ A, const float* __restrict__ B,
    const float* __restrict__ bias, const float* __restrict__ sqf,
    float* __restrict__ C, int M, int N, int K)
{
  __shared__ float As[64][17];
  __shared__ float Bs[16][65];
  const int tid = threadIdx.x;
  const int tx = tid & 15, ty = tid >> 4;
  const int rowBase = blockIdx.y*64, colBase = blockIdx.x*64;
  float acc[4][4] = {{0.f}};

  for (int k0 = 0; k0 < K; k0 += 16){
    #pragma unroll
    for (int p = 0; p < 4; ++p){
      int idx = p*256 + tid;
      int r = idx >> 4, kk = idx & 15;
      int gk = k0 + kk;
      As[r][kk] = (gk < K) ? A[(size_t)(rowBase+r)*K + gk] : 0.f;
    }
    if (!TRANSB){
      #pragma unroll
      for (int p = 0; p < 4; ++p){
        int idx = p*256 + tid;
        int k = idx >> 6, c = idx & 63;
        int gk = k0 + k, gc = colBase + c;
        Bs[k][c] = (gk < K && gc < N) ? B[(size_t)gk*N + gc] : 0.f;
      }
    } else {
      #pragma unroll
      for (int p = 0; p < 4; ++p){
        int idx = p*256 + tid;
        int k = idx & 15, c = idx >> 4;
        int gk = k0 + k, gc = colBase + c;
        Bs[k][c] = (gk < K && gc < N) ? B[(size_t)gc*K + gk] : 0.f;
      }
    }
    __syncthreads();
    #pragma unroll
    for (int k = 0; k < 16; ++k){
      float a[4], b[4];
      #pragma unroll
      for (int i=0;i<4;++i) a[i] = As[ty*4+i][k];
      #pragma unroll
      for (int j=0;j<4;++j) b[j] = Bs[k][tx*4+j];
      #pragma unroll
      for (int i=0;i<4;++i)
        #pragma unroll
        for (int j=0;j<4;++j) acc[i][j] = fmaf(a[i], b[j], acc[i][j]);
    }
    __syncthreads();
  }

  #pragma unroll
  for (int i=0;i<4;++i){
    int row = rowBase + ty*4 + i;
    #pragma unroll
    for (int j=0;j<4;++j){
      int col = colBase + tx*4 + j;
      if (col < N){
        float c = acc[i][j];
        if (EPI == 3) c = sqf[row] + sqf[col] - 2.0f*c;
        if (bias) c += bias[col];
        if (EPI == 1) c = tanhf(c);
        if (EPI == 2) c = 1.0f/(1.0f + expf(-c));
        C[(size_t)row*N + col] = c;
      }
    }
  }
}

// ---------------- kNN: f32 top-10 window + margin candidates (cap 96) ----------------
__global__ __launch_bounds__(256) void knn_select(const float* __restrict__ dists,
                                                  int* __restrict__ cand, int* __restrict__ candc){
  const int row = blockIdx.x, tid = threadIdx.x;
  __shared__ float drow[4096];
  __shared__ float rv[256]; __shared__ int ri[256];
  __shared__ float d10s;
  const float* dr = dists + (size_t)row*4096;
  for (int j = tid; j < 4096; j += 256) drow[j] = dr[j];
  __syncthreads();
  for (int t = 0; t < 10; ++t){
    float bv = 3.4e38f; int bi = 0x7FFFFFFF;
    for (int j = tid; j < 4096; j += 256){
      float v = drow[j];
      if (v < bv || (v == bv && j < bi)){ bv = v; bi = j; }
    }
    rv[tid] = bv; ri[tid] = bi;
    __syncthreads();
    for (int s = 128; s > 0; s >>= 1){
      if (tid < s){
        float ov = rv[tid+s]; int oi = ri[tid+s];
        if (ov < rv[tid] || (ov == rv[tid] && oi < ri[tid])){ rv[tid] = ov; ri[tid] = oi; }
      }
      __syncthreads();
    }
    if (tid == 0){ drow[ri[0]] = 3.4e38f; if (t == 9) d10s = rv[0]; }
    __syncthreads();
  }
  const float thr = d10s + 2.0f;
  if (tid < 64){
    int lane = tid;
    int cnt = 0;
    for (int base = 0; base < 4096; base += 64){
      bool p = dr[base+lane] <= thr;
      unsigned long long mask = __ballot(p);
      if (p){
        int pos = __popcll(mask & ((1ull<<lane)-1ull));
        if (cnt + pos < 96) cand[(size_t)row*96 + cnt + pos] = base + lane;
      }
      cnt += __popcll(mask);
    }
    if (lane == 0) candc[row] = cnt < 96 ? cnt : 96;
  }
}

// ---------------- kNN: f32-MIMIC re-rank of candidates ----------------
__global__ __launch_bounds__(256) void knn_rank32(const float* __restrict__ x,
    const int* __restrict__ cand, const int* __restrict__ candc,
    int* __restrict__ nbrK, int* __restrict__ nbrKc)
{
  const int row = blockIdx.x, tid = threadIdx.x;
  const int wid = tid>>6, lane = tid&63;
  __shared__ float xi[1024];
  __shared__ float cd[96];
  __shared__ float sqi_sh;
  const float* xr = x + (size_t)row*1024;
  for (int k = tid; k < 1024; k += 256) xi[k] = xr[k];
  __syncthreads();
  if (wid == 0){
    float a = 0.f;
    #pragma unroll
    for (int t = 0; t < 16; ++t){ float v = xi[lane + 64*t]; a = fmaf(v, v, a); }
    a += __shfl_xor(a, 16); a += __shfl_xor(a, 32);
    a += __shfl_xor(a, 8);  a += __shfl_xor(a, 4);
    a += __shfl_xor(a, 2);  a += __shfl_xor(a, 1);
    if (lane == 0) sqi_sh = a;
  }
  __syncthreads();
  const float sqi = sqi_sh;
  const int cnt = candc[row];
  for (int s = wid; s < cnt; s += 4){
    int c = cand[(size_t)row*96 + s];
    const float* xc = x + (size_t)c*1024;
    float ad = 0.f, aq = 0.f;
    #pragma unroll
    for (int t = 0; t < 16; ++t){
      int k = lane + 64*t;
      float v = xc[k];
      ad = fmaf(xi[k], v, ad);
      aq = fmaf(v, v, aq);
    }
    ad += __shfl_xor(ad, 16); ad += __shfl_xor(ad, 32);
    ad += __shfl_xor(ad, 8);  ad += __shfl_xor(ad, 4);
    ad += __shfl_xor(ad, 2);  ad += __shfl_xor(ad, 1);
    aq += __shfl_xor(aq, 16); aq += __shfl_xor(aq, 32);
    aq += __shfl_xor(aq, 8);  aq += __shfl_xor(aq, 4);
    aq += __shfl_xor(aq, 2);  aq += __shfl_xor(aq, 1);
    if (lane == 0) cd[s] = (sqi - 2.0f*ad) + aq;
  }
  __syncthreads();
  if (tid == 0){
    int m = 0;
    int lim = cnt < 10 ? cnt : 10;
    for (int t = 0; t < lim; ++t){
      float bd = 3.4e38f; int bs = 0;
      for (int s = 0; s < cnt; ++s){
        if (cd[s] < bd){ bd = cd[s]; bs = s; }
      }
      cd[bs] = 3.4e38f;
      int j = cand[(size_t)row*96 + bs];
      if (j != row && m < 10){ nbrK[row*10 + m] = j; ++m; }
    }
    nbrKc[row] = m;
  }
}

__global__ __launch_bounds__(64) void scatter_k(const int* __restrict__ nbrK, const int* __restrict__ nbrKc,
                                                float* __restrict__ g){
  int row = blockIdx.x, t = threadIdx.x;
  int m = nbrKc[row];
  if (t < m){
    int j = nbrK[row*10 + t];
    g[(size_t)row*4096 + j] = 1.0f;
    g[(size_t)j*4096 + row] = 1.0f;
  }
}

__global__ __launch_bounds__(64) void build_lists(const float* __restrict__ g, int* __restrict__ nbrl,
                                                  int* __restrict__ nbrc, float* __restrict__ dinv){
  int row = blockIdx.x, lane = threadIdx.x;
  const float* gr = g + (size_t)row*4096;
  int cnt = 0;
  for (int base = 0; base < 4096; base += 64){
    bool p = gr[base+lane] != 0.f;
    unsigned long long mask = __ballot(p);
    if (p){
      int pos = __popcll(mask & ((1ull<<lane)-1ull));
      if (cnt + pos < NBR_CAP) nbrl[(size_t)row*NBR_CAP + cnt + pos] = base + lane;
    }
    cnt += __popcll(mask);
  }
  if (lane == 0){
    nbrc[row] = cnt < NBR_CAP ? cnt : NBR_CAP;
    dinv[row] = 1.0f/sqrtf((float)(cnt + 1));
  }
}

// ---------------- SpMM v2: grid (W/64 chunks, rows), block = 64 cols x 4 s-lanes ----------------
__global__ __launch_bounds__(256) void spmm_k(const float* __restrict__ X, const int* __restrict__ nbrl,
    const int* __restrict__ nbrc, const float* __restrict__ dinv, float* __restrict__ out, int W){
  const int row = blockIdx.y;
  const int lane = threadIdx.x & 63;
  const int sl = threadIdx.x >> 6;                 // 0..3
  const int col = blockIdx.x*64 + lane;
  __shared__ int li[NBR_CAP]; __shared__ float lv[NBR_CAP];
  __shared__ float red[4][64];
  const int cnt = nbrc[row];
  for (int t = threadIdx.x; t < cnt; t += 256){
    int j = nbrl[(size_t)row*NBR_CAP + t];
    li[t] = j; lv[t] = dinv[j];
  }
  __syncthreads();
  const float di = dinv[row];
  float p = 0.f;
  if (col < W){
    for (int s = sl; s < cnt; s += 4)
      p = fmaf(lv[s], X[(size_t)li[s]*W + col], p);
    if (sl == 0) p = fmaf(di, X[(size_t)row*W + col], p);
  }
  red[sl][lane] = p;
  __syncthreads();
  if (sl == 0 && col < W){
    float acc = red[0][lane] + red[1][lane] + red[2][lane] + red[3][lane];
    out[(size_t)row*W + col] = di*acc;
  }
}

// ---------------- q = softmax(z @ lc_w + lc_b) ----------------
__global__ __launch_bounds__(64) void q_kernel(const float* __restrict__ z, const float* __restrict__ lcw,
                                               const float* __restrict__ lcb, float* __restrict__ qs){
  int row = blockIdx.x, lane = threadIdx.x;
  __shared__ float ls[10];
  const float* zr = z + (size_t)row*512;
  for (int c = 0; c < 10; ++c){
    float a = 0.f;
    for (int k = lane; k < 512; k += 64) a += zr[k]*lcw[k*10 + c];
    for (int o = 32; o > 0; o >>= 1) a += __shfl_down(a, o);
    if (lane == 0) ls[c] = a + lcb[c];
  }
  __syncthreads();
  if (lane == 0){
    float m = ls[0];
    for (int c = 1; c < 10; ++c) m = fmaxf(m, ls[c]);
    float sum = 0.f, e[10];
    for (int c = 0; c < 10; ++c){ e[c] = expf(ls[c]-m); sum += e[c]; }
    for (int c = 0; c < 10; ++c) qs[(size_t)row*10 + c] = e[c]/sum;
  }
}

// ---------------- h row-normalize ----------------
__global__ __launch_bounds__(64) void hnorm_k(const float* __restrict__ hp, float* __restrict__ hs){
  int row = blockIdx.x, lane = threadIdx.x;
  const float* hr = hp + (size_t)row*128;
  float v0 = hr[lane], v1 = hr[lane+64];
  float a = v0*v0 + v1*v1;
  for (int o = 32; o > 0; o >>= 1) a += __shfl_down(a, o);
  float nrm = sqrtf(__shfl(a, 0));
  hs[(size_t)row*128 + lane]      = v0/nrm;
  hs[(size_t)row*128 + lane + 64] = v1/nrm;
}

extern "C" void kernel_launch(void* const* d_in, const int* in_sizes, int n_in,
                              void* d_out, int out_size, void* d_ws, size_t ws_size,
                              hipStream_t stream)
{
  const float* xs  = (const float*)d_in[0];
  const float* ew1 = (const float*)d_in[1];
  const float* eb1 = (const float*)d_in[2];
  const float* ew2 = (const float*)d_in[3];
  const float* eb2 = (const float*)d_in[4];
  const float* eWp = (const float*)d_in[5];
  const float* dW1 = (const float*)d_in[6];
  const float* dw1 = (const float*)d_in[7];
  const float* db1 = (const float*)d_in[8];
  const float* dw2 = (const float*)d_in[9];
  const float* db2 = (const float*)d_in[10];
  const float* fcw = (const float*)d_in[11];
  const float* fcb = (const float*)d_in[12];
  const float* lcw = (const float*)d_in[13];
  const float* lcb = (const float*)d_in[14];

  float* out = (float*)d_out;   // OUTPUT IS FLOAT32
  const size_t HS0 = 0;
  const size_t QS0 = HS0 + (size_t)2*4096*128;
  const size_t XR0 = QS0 + (size_t)2*4096*10;
  const size_t ZS0 = XR0 + (size_t)2*4096*1024;
  const size_t GS0 = ZS0 + (size_t)2*4096*512;
  const size_t AR0 = GS0 + (size_t)2*4096*4096;

  void* sp = nullptr;
  hipGetSymbolAddress(&sp, HIP_SYMBOL(g_scratch));
  if (!sp) return;
  char* ws = (char*)sp;

  float* dists = (float*)(ws + 0);            // 64MB
  float* o1    = (float*)(ws + 67108864);     // 29.5MB (h11 aliases)
  float* so1   = (float*)(ws + 96600064);     // 29.5MB (sh11 aliases)
  float* sx    = (float*)(ws + 126091264);    // 16MB
  float* sh1   = (float*)(ws + 142868480);    // 8MB
  float* zw    = (float*)(ws + 151257088);    // 8MB
  float* h1    = (float*)(ws + 159645696);    // 8MB
  float* hpre  = (float*)(ws + 168034304);    // 2MB
  double* sq64 = (double*)(ws + 170131456);
  float* sqf   = (float*)(ws + 170164224);
  int* cand    = (int*)(ws + 170180608);      // 4096*96*4
  int* candc   = (int*)(ws + 171753472);
  int* nbrK    = (int*)(ws + 171769856);
  int* nbrKc   = (int*)(ws + 171933696);
  int* nbrl    = (int*)(ws + 171950080);      // 32MB
  int* nbrc    = (int*)(ws + 205504512);
  float* dinv  = (float*)(ws + 205520896);
  float* h11   = o1;
  float* sh11  = so1;

  hipMemsetAsync(out + GS0, 0, (size_t)2*4096*4096*sizeof(float), stream);

  for (int v = 0; v < 2; ++v){
    const float* x    = xs  + (size_t)v*4096*1024;
    const float* w1   = ew1 + (size_t)v*1024*1800;
    const float* b1   = eb1 + (size_t)v*1800;
    const float* w2   = ew2 + (size_t)v*1800*512;
    const float* b2   = eb2 + (size_t)v*512;
    const float* We   = eWp + (size_t)v*512*512;
    const float* dWv  = dW1 + (size_t)v*512*512;
    const float* dw1v = dw1 + (size_t)v*512*1800;
    const float* db1v = db1 + (size_t)v*1800;
    const float* dw2v = dw2 + (size_t)v*1800*1024;
    const float* db2v = db2 + (size_t)v*1024;
    float* hs_o = out + HS0 + (size_t)v*4096*128;
    float* qs_o = out + QS0 + (size_t)v*4096*10;
    float* xr_o = out + XR0 + (size_t)v*4096*1024;
    float* zs_o = out + ZS0 + (size_t)v*4096*512;
    float* gs_o = out + GS0 + (size_t)v*4096*4096;
    float* ar_o = out + AR0 + (size_t)v*4096*4096;

    // ---- graph ----
    sq_kernel<<<1024,256,0,stream>>>(x, sq64, sqf);
    sgemm_k<true,3><<<dim3(64,64),256,0,stream>>>(x,x,nullptr,sqf,dists,4096,4096,1024);
    knn_select<<<4096,256,0,stream>>>(dists, cand, candc);
    knn_rank32<<<4096,256,0,stream>>>(x, cand, candc, nbrK, nbrKc);
    scatter_k<<<4096,64,0,stream>>>(nbrK, nbrKc, gs_o);
    build_lists<<<4096,64,0,stream>>>(gs_o, nbrl, nbrc, dinv);

    // ---- encoder ----
    spmm_k<<<dim3(16,4096),256,0,stream>>>(x, nbrl, nbrc, dinv, sx, 1024);
    sgemm_k<false,1><<<dim3(29,64),256,0,stream>>>(sx,w1,b1,nullptr,o1,4096,1800,1024);
    spmm_k<<<dim3(29,4096),256,0,stream>>>(o1, nbrl, nbrc, dinv, so1, 1800);
    sgemm_k<false,1><<<dim3(8,64),256,0,stream>>>(so1,w2,b2,nullptr,zs_o,4096,512,1800);

    // ---- a = sigmoid((z@eW)@z^T) ----
    sgemm_k<false,0><<<dim3(8,64),256,0,stream>>>(zs_o,We,nullptr,nullptr,zw,4096,512,512);
    sgemm_k<true,2><<<dim3(64,64),256,0,stream>>>(zw,zs_o,nullptr,nullptr,ar_o,4096,4096,512);

    // ---- heads ----
    sgemm_k<false,0><<<dim3(2,64),256,0,stream>>>(zs_o,fcw,fcb,nullptr,hpre,4096,128,512);
    hnorm_k<<<4096,64,0,stream>>>(hpre, hs_o);
    q_kernel<<<4096,64,0,stream>>>(zs_o, lcw, lcb, qs_o);

    // ---- decoder ----
    sgemm_k<false,1><<<dim3(8,64),256,0,stream>>>(zs_o,dWv,nullptr,nullptr,h1,4096,512,512);
    spmm_k<<<dim3(8,4096),256,0,stream>>>(h1, nbrl, nbrc, dinv, sh1, 512);
    sgemm_k<false,1><<<dim3(29,64),256,0,stream>>>(sh1,dw1v,db1v,nullptr,h11,4096,1800,512);
    spmm_k<<<dim3(29,4096),256,0,stream>>>(h11, nbrl, nbrc, dinv, sh11, 1800);
    sgemm_k<false,1><<<dim3(16,64),256,0,stream>>>(sh11,dw2v,db2v,nullptr,xr_o,4096,1024,1800);
  }
}

// Round 13
// 3873.108 us; speedup vs baseline: 2.6852x; 1.8077x over previous
//
#include <hip/hip_runtime.h>
#include <math.h>
#include <stdint.h>

typedef uint16_t u16;
typedef __attribute__((ext_vector_type(8))) short short8;
typedef __attribute__((ext_vector_type(8))) __bf16 bf16x8;
typedef __attribute__((ext_vector_type(4))) float f32x4;
union V8 { short8 s; bf16x8 b; };

__device__ __align__(256) char g_scratch[234881024];  // 224 MB

#define NBR_CAP 2048

__device__ inline float bf2f(u16 u){ return __uint_as_float(((uint32_t)u)<<16); }
__device__ inline u16 f2bf(float f){
  uint32_t x = __float_as_uint(f);
  uint32_t r = (x + 0x7FFFu + ((x>>16)&1u)) >> 16;
  return (u16)r;
}

// ---------------- sq ----------------
__global__ __launch_bounds__(256) void sq_kernel(const float* __restrict__ x,
                                                 float* __restrict__ sqf){
  int wid = threadIdx.x >> 6, lane = threadIdx.x & 63;
  int row = blockIdx.x*4 + wid;
  const float* xr = x + (size_t)row*1024;
  double acc = 0.0;
  for (int k = lane; k < 1024; k += 64){ float v = xr[k]; acc += (double)v*(double)v; }
  for (int o = 32; o > 0; o >>= 1) acc += __shfl_down(acc, o);
  if (lane == 0) sqf[row] = (float)acc;
}

// ---------------- split f32 -> bf16 hi + lo ----------------
__global__ __launch_bounds__(256) void split_k(const float* __restrict__ x, u16* __restrict__ h,
                                               u16* __restrict__ l, int n){
  int i = blockIdx.x*256 + threadIdx.x;
  int stride = gridDim.x*256;
  for (; i < n; i += stride){
    float v = x[i];
    u16 hh = f2bf(v);
    h[i] = hh;
    l[i] = f2bf(v - bf2f(hh));
  }
}

// ---------------- split-bf16 MFMA GEMM, 128x128 tile, BK=32, 3-term ----------------
// EPI: 0=none 1=tanh 2=sigmoid 3=dist(sq_i+sq_j-2c)   [validated R3==R4]
template<bool TRANSB, int EPI>
__global__ __launch_bounds__(256) void gemm_bf(
    const u16* __restrict__ A0, const u16* __restrict__ A1,
    const u16* __restrict__ B0, const u16* __restrict__ B1,
    const float* __restrict__ bias, const float* __restrict__ sqf,
    float* __restrict__ C, int M, int N, int K)
{
  __shared__ u16 As[2][128][40];
  __shared__ u16 Bs[2][128][40];
  const int tid = threadIdx.x;
  const int rowBase = blockIdx.y*128, colBase = blockIdx.x*128;
  const int wid = tid>>6, lane = tid&63;
  const int wr = (wid>>1)*64, wc = (wid&1)*64;
  const int lrow = lane&15, lq = lane>>4;

  f32x4 acc[4][4];
  #pragma unroll
  for (int m=0;m<4;++m)
    #pragma unroll
    for (int n=0;n<4;++n) acc[m][n] = (f32x4){0.f,0.f,0.f,0.f};

  const u16* Ap[2] = {A0, A1};
  const u16* Bp[2] = {B0, B1};

  for (int k0 = 0; k0 < K; k0 += 32){
    #pragma unroll
    for (int s=0; s<2; ++s){
      #pragma unroll
      for (int p=0;p<2;++p){
        int idx = p*256 + tid;
        int r = idx>>2, c8 = (idx&3)<<3;
        int gk = k0 + c8;
        short8 v = {0,0,0,0,0,0,0,0};
        if (gk < K) v = *(const short8*)(Ap[s] + (size_t)(rowBase+r)*K + gk);
        *(short8*)&As[s][r][c8] = v;
      }
    }
    #pragma unroll
    for (int s=0; s<2; ++s){
      if (TRANSB){
        #pragma unroll
        for (int p=0;p<2;++p){
          int idx = p*256 + tid;
          int r = idx>>2, c8 = (idx&3)<<3;
          int gn = colBase + r, gk = k0 + c8;
          short8 v = {0,0,0,0,0,0,0,0};
          if (gk < K && gn < N) v = *(const short8*)(Bp[s] + (size_t)gn*K + gk);
          *(short8*)&Bs[s][r][c8] = v;
        }
      } else {
        #pragma unroll
        for (int p=0;p<2;++p){
          int idx = p*256 + tid;
          int kr = idx>>4, n8 = (idx&15)<<3;
          int gk = k0 + kr, gn = colBase + n8;
          short8 v = {0,0,0,0,0,0,0,0};
          if (gk < K && gn < N) v = *(const short8*)(Bp[s] + (size_t)gk*N + gn);
          #pragma unroll
          for (int e=0;e<8;++e) Bs[s][n8+e][kr] = (u16)v[e];
        }
      }
    }
    __syncthreads();
    V8 af[2][4], bfr[2][4];
    #pragma unroll
    for (int s=0;s<2;++s)
      #pragma unroll
      for (int m=0;m<4;++m)
        af[s][m].s = *(const short8*)&As[s][wr + m*16 + lrow][lq<<3];
    #pragma unroll
    for (int s=0;s<2;++s)
      #pragma unroll
      for (int n=0;n<4;++n)
        bfr[s][n].s = *(const short8*)&Bs[s][wc + n*16 + lrow][lq<<3];
    #pragma unroll
    for (int m=0;m<4;++m)
      #pragma unroll
      for (int n=0;n<4;++n){
        acc[m][n] = __builtin_amdgcn_mfma_f32_16x16x32_bf16(af[0][m].b, bfr[0][n].b, acc[m][n], 0,0,0);
        acc[m][n] = __builtin_amdgcn_mfma_f32_16x16x32_bf16(af[1][m].b, bfr[0][n].b, acc[m][n], 0,0,0);
        acc[m][n] = __builtin_amdgcn_mfma_f32_16x16x32_bf16(af[0][m].b, bfr[1][n].b, acc[m][n], 0,0,0);
      }
    __syncthreads();
  }

  #pragma unroll
  for (int m=0;m<4;++m)
    #pragma unroll
    for (int n=0;n<4;++n)
      #pragma unroll
      for (int r=0;r<4;++r){
        int row = rowBase + wr + m*16 + lq*4 + r;
        int col = colBase + wc + n*16 + lrow;
        if (col < N){
          float c = acc[m][n][r];
          if (EPI == 3) c = sqf[row] + sqf[col] - 2.0f*c;
          if (bias) c += bias[col];
          if (EPI == 1) c = tanhf(c);
          if (EPI == 2) c = 1.0f/(1.0f + expf(-c));
          C[(size_t)row*N + col] = c;
        }
      }
}

// ---------------- f32 LDS-tiled GEMM (small hpre only) ----------------
template<bool TRANSB, int EPI>
__global__ __launch_bounds__(256) void sgemm_k(
    const float* __restrict__ A, const float* __restrict__ B,
    const float* __restrict__ bias, const float* __restrict__ sqf,
    float* __restrict__ C, int M, int N, int K)
{
  __shared__ float As[64][17];
  __shared__ float Bs[16][65];
  const int tid = threadIdx.x;
  const int tx = tid & 15, ty = tid >> 4;
  const int rowBase = blockIdx.y*64, colBase = blockIdx.x*64;
  float acc[4][4] = {{0.f}};

  for (int k0 = 0; k0 < K; k0 += 16){
    #pragma unroll
    for (int p = 0; p < 4; ++p){
      int idx = p*256 + tid;
      int r = idx >> 4, kk = idx & 15;
      int gk = k0 + kk;
      As[r][kk] = (gk < K) ? A[(size_t)(rowBase+r)*K + gk] : 0.f;
    }
    if (!TRANSB){
      #pragma unroll
      for (int p = 0; p < 4; ++p){
        int idx = p*256 + tid;
        int k = idx >> 6, c = idx & 63;
        int gk = k0 + k, gc = colBase + c;
        Bs[k][c] = (gk < K && gc < N) ? B[(size_t)gk*N + gc] : 0.f;
      }
    } else {
      #pragma unroll
      for (int p = 0; p < 4; ++p){
        int idx = p*256 + tid;
        int k = idx & 15, c = idx >> 4;
        int gk = k0 + k, gc = colBase + c;
        Bs[k][c] = (gk < K && gc < N) ? B[(size_t)gc*K + gk] : 0.f;
      }
    }
    __syncthreads();
    #pragma unroll
    for (int k = 0; k < 16; ++k){
      float a[4], b[4];
      #pragma unroll
      for (int i=0;i<4;++i) a[i] = As[ty*4+i][k];
      #pragma unroll
      for (int j=0;j<4;++j) b[j] = Bs[k][tx*4+j];
      #pragma unroll
      for (int i=0;i<4;++i)
        #pragma unroll
        for (int j=0;j<4;++j) acc[i][j] = fmaf(a[i], b[j], acc[i][j]);
    }
    __syncthreads();
  }

  #pragma unroll
  for (int i=0;i<4;++i){
    int row = rowBase + ty*4 + i;
    #pragma unroll
    for (int j=0;j<4;++j){
      int col = colBase + tx*4 + j;
      if (col < N){
        float c = acc[i][j];
        if (bias) c += bias[col];
        if (EPI == 1) c = tanhf(c);
        C[(size_t)row*N + col] = c;
      }
    }
  }
}

// ---------------- kNN: f32 top-10 window + margin candidates (cap 96) ----------------
__global__ __launch_bounds__(256) void knn_select(const float* __restrict__ dists,
                                                  int* __restrict__ cand, int* __restrict__ candc){
  const int row = blockIdx.x, tid = threadIdx.x;
  __shared__ float drow[4096];
  __shared__ float rv[256]; __shared__ int ri[256];
  __shared__ float d10s;
  const float* dr = dists + (size_t)row*4096;
  for (int j = tid; j < 4096; j += 256) drow[j] = dr[j];
  __syncthreads();
  for (int t = 0; t < 10; ++t){
    float bv = 3.4e38f; int bi = 0x7FFFFFFF;
    for (int j = tid; j < 4096; j += 256){
      float v = drow[j];
      if (v < bv || (v == bv && j < bi)){ bv = v; bi = j; }
    }
    rv[tid] = bv; ri[tid] = bi;
    __syncthreads();
    for (int s = 128; s > 0; s >>= 1){
      if (tid < s){
        float ov = rv[tid+s]; int oi = ri[tid+s];
        if (ov < rv[tid] || (ov == rv[tid] && oi < ri[tid])){ rv[tid] = ov; ri[tid] = oi; }
      }
      __syncthreads();
    }
    if (tid == 0){ drow[ri[0]] = 3.4e38f; if (t == 9) d10s = rv[0]; }
    __syncthreads();
  }
  const float thr = d10s + 2.0f;
  if (tid < 64){
    int lane = tid;
    int cnt = 0;
    for (int base = 0; base < 4096; base += 64){
      bool p = dr[base+lane] <= thr;
      unsigned long long mask = __ballot(p);
      if (p){
        int pos = __popcll(mask & ((1ull<<lane)-1ull));
        if (cnt + pos < 96) cand[(size_t)row*96 + cnt + pos] = base + lane;
      }
      cnt += __popcll(mask);
    }
    if (lane == 0) candc[row] = cnt < 96 ? cnt : 96;
  }
}

// ---------------- kNN: f32-MIMIC re-rank ----------------
__global__ __launch_bounds__(256) void knn_rank32(const float* __restrict__ x,
    const int* __restrict__ cand, const int* __restrict__ candc,
    int* __restrict__ nbrK, int* __restrict__ nbrKc)
{
  const int row = blockIdx.x, tid = threadIdx.x;
  const int wid = tid>>6, lane = tid&63;
  __shared__ float xi[1024];
  __shared__ float cd[96];
  __shared__ float sqi_sh;
  const float* xr = x + (size_t)row*1024;
  for (int k = tid; k < 1024; k += 256) xi[k] = xr[k];
  __syncthreads();
  if (wid == 0){
    float a = 0.f;
    #pragma unroll
    for (int t = 0; t < 16; ++t){ float v = xi[lane + 64*t]; a = fmaf(v, v, a); }
    a += __shfl_xor(a, 16); a += __shfl_xor(a, 32);
    a += __shfl_xor(a, 8);  a += __shfl_xor(a, 4);
    a += __shfl_xor(a, 2);  a += __shfl_xor(a, 1);
    if (lane == 0) sqi_sh = a;
  }
  __syncthreads();
  const float sqi = sqi_sh;
  const int cnt = candc[row];
  for (int s = wid; s < cnt; s += 4){
    int c = cand[(size_t)row*96 + s];
    const float* xc = x + (size_t)c*1024;
    float ad = 0.f, aq = 0.f;
    #pragma unroll
    for (int t = 0; t < 16; ++t){
      int k = lane + 64*t;
      float v = xc[k];
      ad = fmaf(xi[k], v, ad);
      aq = fmaf(v, v, aq);
    }
    ad += __shfl_xor(ad, 16); ad += __shfl_xor(ad, 32);
    ad += __shfl_xor(ad, 8);  ad += __shfl_xor(ad, 4);
    ad += __shfl_xor(ad, 2);  ad += __shfl_xor(ad, 1);
    aq += __shfl_xor(aq, 16); aq += __shfl_xor(aq, 32);
    aq += __shfl_xor(aq, 8);  aq += __shfl_xor(aq, 4);
    aq += __shfl_xor(aq, 2);  aq += __shfl_xor(aq, 1);
    if (lane == 0) cd[s] = (sqi - 2.0f*ad) + aq;
  }
  __syncthreads();
  if (tid == 0){
    int m = 0;
    int lim = cnt < 10 ? cnt : 10;
    for (int t = 0; t < lim; ++t){
      float bd = 3.4e38f; int bs = 0;
      for (int s = 0; s < cnt; ++s){
        if (cd[s] < bd){ bd = cd[s]; bs = s; }
      }
      cd[bs] = 3.4e38f;
      int j = cand[(size_t)row*96 + bs];
      if (j != row && m < 10){ nbrK[row*10 + m] = j; ++m; }
    }
    nbrKc[row] = m;
  }
}

__global__ __launch_bounds__(64) void scatter_k(const int* __restrict__ nbrK, const int* __restrict__ nbrKc,
                                                float* __restrict__ g){
  int row = blockIdx.x, t = threadIdx.x;
  int m = nbrKc[row];
  if (t < m){
    int j = nbrK[row*10 + t];
    g[(size_t)row*4096 + j] = 1.0f;
    g[(size_t)j*4096 + row] = 1.0f;
  }
}

__global__ __launch_bounds__(64) void build_lists(const float* __restrict__ g, int* __restrict__ nbrl,
                                                  int* __restrict__ nbrc, float* __restrict__ dinv){
  int row = blockIdx.x, lane = threadIdx.x;
  const float* gr = g + (size_t)row*4096;
  int cnt = 0;
  for (int base = 0; base < 4096; base += 64){
    bool p = gr[base+lane] != 0.f;
    unsigned long long mask = __ballot(p);
    if (p){
      int pos = __popcll(mask & ((1ull<<lane)-1ull));
      if (cnt + pos < NBR_CAP) nbrl[(size_t)row*NBR_CAP + cnt + pos] = base + lane;
    }
    cnt += __popcll(mask);
  }
  if (lane == 0){
    nbrc[row] = cnt < NBR_CAP ? cnt : NBR_CAP;
    dinv[row] = 1.0f/sqrtf((float)(cnt + 1));
  }
}

// ---------------- SpMM v2 ----------------
__global__ __launch_bounds__(256) void spmm_k(const float* __restrict__ X, const int* __restrict__ nbrl,
    const int* __restrict__ nbrc, const float* __restrict__ dinv, float* __restrict__ out, int W){
  const int row = blockIdx.y;
  const int lane = threadIdx.x & 63;
  const int sl = threadIdx.x >> 6;
  const int col = blockIdx.x*64 + lane;
  __shared__ int li[NBR_CAP]; __shared__ float lv[NBR_CAP];
  __shared__ float red[4][64];
  const int cnt = nbrc[row];
  for (int t = threadIdx.x; t < cnt; t += 256){
    int j = nbrl[(size_t)row*NBR_CAP + t];
    li[t] = j; lv[t] = dinv[j];
  }
  __syncthreads();
  const float di = dinv[row];
  float p = 0.f;
  if (col < W){
    for (int s = sl; s < cnt; s += 4)
      p = fmaf(lv[s], X[(size_t)li[s]*W + col], p);
    if (sl == 0) p = fmaf(di, X[(size_t)row*W + col], p);
  }
  red[sl][lane] = p;
  __syncthreads();
  if (sl == 0 && col < W){
    float acc = red[0][lane] + red[1][lane] + red[2][lane] + red[3][lane];
    out[(size_t)row*W + col] = di*acc;
  }
}

// ---------------- q = softmax(z @ lc_w + lc_b) ----------------
__global__ __launch_bounds__(64) void q_kernel(const float* __restrict__ z, const float* __restrict__ lcw,
                                               const float* __restrict__ lcb, float* __restrict__ qs){
  int row = blockIdx.x, lane = threadIdx.x;
  __shared__ float ls[10];
  const float* zr = z + (size_t)row*512;
  for (int c = 0; c < 10; ++c){
    float a = 0.f;
    for (int k = lane; k < 512; k += 64) a += zr[k]*lcw[k*10 + c];
    for (int o = 32; o > 0; o >>= 1) a += __shfl_down(a, o);
    if (lane == 0) ls[c] = a + lcb[c];
  }
  __syncthreads();
  if (lane == 0){
    float m = ls[0];
    for (int c = 1; c < 10; ++c) m = fmaxf(m, ls[c]);
    float sum = 0.f, e[10];
    for (int c = 0; c < 10; ++c){ e[c] = expf(ls[c]-m); sum += e[c]; }
    for (int c = 0; c < 10; ++c) qs[(size_t)row*10 + c] = e[c]/sum;
  }
}

// ---------------- h row-normalize ----------------
__global__ __launch_bounds__(64) void hnorm_k(const float* __restrict__ hp, float* __restrict__ hs){
  int row = blockIdx.x, lane = threadIdx.x;
  const float* hr = hp + (size_t)row*128;
  float v0 = hr[lane], v1 = hr[lane+64];
  float a = v0*v0 + v1*v1;
  for (int o = 32; o > 0; o >>= 1) a += __shfl_down(a, o);
  float nrm = sqrtf(__shfl(a, 0));
  hs[(size_t)row*128 + lane]      = v0/nrm;
  hs[(size_t)row*128 + lane + 64] = v1/nrm;
}

extern "C" void kernel_launch(void* const* d_in, const int* in_sizes, int n_in,
                              void* d_out, int out_size, void* d_ws, size_t ws_size,
                              hipStream_t stream)
{
  const float* xs  = (const float*)d_in[0];
  const float* ew1 = (const float*)d_in[1];
  const float* eb1 = (const float*)d_in[2];
  const float* ew2 = (const float*)d_in[3];
  const float* eb2 = (const float*)d_in[4];
  const float* eWp = (const float*)d_in[5];
  const float* dW1 = (const float*)d_in[6];
  const float* dw1 = (const float*)d_in[7];
  const float* db1 = (const float*)d_in[8];
  const float* dw2 = (const float*)d_in[9];
  const float* db2 = (const float*)d_in[10];
  const float* fcw = (const float*)d_in[11];
  const float* fcb = (const float*)d_in[12];
  const float* lcw = (const float*)d_in[13];
  const float* lcb = (const float*)d_in[14];

  float* out = (float*)d_out;
  const size_t HS0 = 0;
  const size_t QS0 = HS0 + (size_t)2*4096*128;
  const size_t XR0 = QS0 + (size_t)2*4096*10;
  const size_t ZS0 = XR0 + (size_t)2*4096*1024;
  const size_t GS0 = ZS0 + (size_t)2*4096*512;
  const size_t AR0 = GS0 + (size_t)2*4096*4096;

  void* sp = nullptr;
  hipGetSymbolAddress(&sp, HIP_SYMBOL(g_scratch));
  if (!sp) return;
  char* ws = (char*)sp;

  // region 0..64MB: dists during graph phase; split buffers afterwards
  float* dists = (float*)(ws + 0);
  u16* GAH = (u16*)(ws + 0);           // 14.75MB (<=4096x1800)
  u16* GAL = (u16*)(ws + 14745600);
  u16* GWH = (u16*)(ws + 29491200);    // 3.69MB (<=1800x1024)
  u16* GWL = (u16*)(ws + 33177600);
  u16* ZH  = (u16*)(ws + 36864000);    // 4MB (4096x512)
  u16* ZL  = (u16*)(ws + 41058304);
  u16* WH  = (u16*)(ws + 45252608);
  u16* WL  = (u16*)(ws + 49446912);    // ends 53.6MB < 64MB

  float* o1    = (float*)(ws + 67108864);     // 29.5MB (h11 aliases; XH/XL alias pre-o1)
  u16* XH = (u16*)(ws + 67108864);            // 8MB (4096x1024)
  u16* XL = (u16*)(ws + 75497472);
  float* so1   = (float*)(ws + 96600064);     // 29.5MB (sh11 aliases)
  float* sx    = (float*)(ws + 126091264);    // 16MB
  float* sh1   = (float*)(ws + 142868480);    // 8MB
  float* zw    = (float*)(ws + 151257088);    // 8MB
  float* h1    = (float*)(ws + 159645696);    // 8MB
  float* hpre  = (float*)(ws + 168034304);    // 2MB
  float* sqf   = (float*)(ws + 170164224);
  int* cand    = (int*)(ws + 170180608);
  int* candc   = (int*)(ws + 171753472);
  int* nbrK    = (int*)(ws + 171769856);
  int* nbrKc   = (int*)(ws + 171933696);
  int* nbrl    = (int*)(ws + 171950080);      // 32MB
  int* nbrc    = (int*)(ws + 205504512);
  float* dinv  = (float*)(ws + 205520896);
  float* h11   = o1;
  float* sh11  = so1;

  hipMemsetAsync(out + GS0, 0, (size_t)2*4096*4096*sizeof(float), stream);

  for (int v = 0; v < 2; ++v){
    const float* x    = xs  + (size_t)v*4096*1024;
    const float* w1   = ew1 + (size_t)v*1024*1800;
    const float* b1   = eb1 + (size_t)v*1800;
    const float* w2   = ew2 + (size_t)v*1800*512;
    const float* b2   = eb2 + (size_t)v*512;
    const float* We   = eWp + (size_t)v*512*512;
    const float* dWv  = dW1 + (size_t)v*512*512;
    const float* dw1v = dw1 + (size_t)v*512*1800;
    const float* db1v = db1 + (size_t)v*1800;
    const float* dw2v = dw2 + (size_t)v*1800*1024;
    const float* db2v = db2 + (size_t)v*1024;
    float* hs_o = out + HS0 + (size_t)v*4096*128;
    float* qs_o = out + QS0 + (size_t)v*4096*10;
    float* xr_o = out + XR0 + (size_t)v*4096*1024;
    float* zs_o = out + ZS0 + (size_t)v*4096*512;
    float* gs_o = out + GS0 + (size_t)v*4096*4096;
    float* ar_o = out + AR0 + (size_t)v*4096*4096;

    // ---- graph ----
    sq_kernel<<<1024,256,0,stream>>>(x, sqf);
    split_k<<<2048,256,0,stream>>>(x, XH, XL, 4096*1024);
    gemm_bf<true,3><<<dim3(32,32),256,0,stream>>>(XH,XL,XH,XL,nullptr,sqf,dists,4096,4096,1024);
    knn_select<<<4096,256,0,stream>>>(dists, cand, candc);
    knn_rank32<<<4096,256,0,stream>>>(x, cand, candc, nbrK, nbrKc);
    scatter_k<<<4096,64,0,stream>>>(nbrK, nbrKc, gs_o);
    build_lists<<<4096,64,0,stream>>>(gs_o, nbrl, nbrc, dinv);

    // ---- encoder ----
    spmm_k<<<dim3(16,4096),256,0,stream>>>(x, nbrl, nbrc, dinv, sx, 1024);
    split_k<<<2048,256,0,stream>>>(sx, GAH, GAL, 4096*1024);
    split_k<<<2048,256,0,stream>>>(w1, GWH, GWL, 1024*1800);
    gemm_bf<false,1><<<dim3(15,32),256,0,stream>>>(GAH,GAL,GWH,GWL,b1,nullptr,o1,4096,1800,1024);
    spmm_k<<<dim3(29,4096),256,0,stream>>>(o1, nbrl, nbrc, dinv, so1, 1800);
    split_k<<<2048,256,0,stream>>>(so1, GAH, GAL, 4096*1800);
    split_k<<<2048,256,0,stream>>>(w2, GWH, GWL, 1800*512);
    gemm_bf<false,1><<<dim3(4,32),256,0,stream>>>(GAH,GAL,GWH,GWL,b2,nullptr,zs_o,4096,512,1800);

    // ---- a = sigmoid((z@eW)@z^T) ----
    split_k<<<2048,256,0,stream>>>(zs_o, ZH, ZL, 4096*512);
    split_k<<<2048,256,0,stream>>>(We, GWH, GWL, 512*512);
    gemm_bf<false,0><<<dim3(4,32),256,0,stream>>>(ZH,ZL,GWH,GWL,nullptr,nullptr,zw,4096,512,512);
    split_k<<<2048,256,0,stream>>>(zw, WH, WL, 4096*512);
    gemm_bf<true,2><<<dim3(32,32),256,0,stream>>>(WH,WL,ZH,ZL,nullptr,nullptr,ar_o,4096,4096,512);

    // ---- heads ----
    sgemm_k<false,0><<<dim3(2,64),256,0,stream>>>(zs_o,fcw,fcb,nullptr,hpre,4096,128,512);
    hnorm_k<<<4096,64,0,stream>>>(hpre, hs_o);
    q_kernel<<<4096,64,0,stream>>>(zs_o, lcw, lcb, qs_o);

    // ---- decoder ----
    split_k<<<2048,256,0,stream>>>(dWv, GWH, GWL, 512*512);
    gemm_bf<false,1><<<dim3(4,32),256,0,stream>>>(ZH,ZL,GWH,GWL,nullptr,nullptr,h1,4096,512,512);
    spmm_k<<<dim3(8,4096),256,0,stream>>>(h1, nbrl, nbrc, dinv, sh1, 512);
    split_k<<<2048,256,0,stream>>>(sh1, GAH, GAL, 4096*512);
    split_k<<<2048,256,0,stream>>>(dw1v, GWH, GWL, 512*1800);
    gemm_bf<false,1><<<dim3(15,32),256,0,stream>>>(GAH,GAL,GWH,GWL,db1v,nullptr,h11,4096,1800,512);
    spmm_k<<<dim3(29,4096),256,0,stream>>>(h11, nbrl, nbrc, dinv, sh11, 1800);
    split_k<<<2048,256,0,stream>>>(sh11, GAH, GAL, 4096*1800);
    split_k<<<2048,256,0,stream>>>(dw2v, GWH, GWL, 1800*1024);
    gemm_bf<false,1><<<dim3(8,32),256,0,stream>>>(GAH,GAL,GWH,GWL,db2v,nullptr,xr_o,4096,1024,1800);
  }
}

// Round 14
// 3351.420 us; speedup vs baseline: 3.1032x; 1.1557x over previous
//
#include <hip/hip_runtime.h>
#include <math.h>
#include <stdint.h>

typedef uint16_t u16;
typedef __attribute__((ext_vector_type(8))) short short8;
typedef __attribute__((ext_vector_type(8))) __bf16 bf16x8;
typedef __attribute__((ext_vector_type(4))) float f32x4;
union V8 { short8 s; bf16x8 b; };

__device__ __align__(256) char g_scratch[234881024];  // 224 MB

#define NBR_CAP 2048

__device__ inline float bf2f(u16 u){ return __uint_as_float(((uint32_t)u)<<16); }
__device__ inline u16 f2bf(float f){
  uint32_t x = __float_as_uint(f);
  uint32_t r = (x + 0x7FFFu + ((x>>16)&1u)) >> 16;
  return (u16)r;
}

// ---------------- sq ----------------
__global__ __launch_bounds__(256) void sq_kernel(const float* __restrict__ x,
                                                 float* __restrict__ sqf){
  int wid = threadIdx.x >> 6, lane = threadIdx.x & 63;
  int row = blockIdx.x*4 + wid;
  const float* xr = x + (size_t)row*1024;
  double acc = 0.0;
  for (int k = lane; k < 1024; k += 64){ float v = xr[k]; acc += (double)v*(double)v; }
  for (int o = 32; o > 0; o >>= 1) acc += __shfl_down(acc, o);
  if (lane == 0) sqf[row] = (float)acc;
}

// ---------------- split f32 -> bf16 hi (+ optional lo) ----------------
__global__ __launch_bounds__(256) void split_k(const float* __restrict__ x, u16* __restrict__ h,
                                               u16* __restrict__ l, int n){
  int i = blockIdx.x*256 + threadIdx.x;
  int stride = gridDim.x*256;
  for (; i < n; i += stride){
    float v = x[i];
    u16 hh = f2bf(v);
    h[i] = hh;
    if (l) l[i] = f2bf(v - bf2f(hh));
  }
}

// ---------------- transpose + split: w[K][N] -> th/tl [N][K] ----------------
__global__ __launch_bounds__(256) void tsplit_k(const float* __restrict__ w, u16* __restrict__ th,
                                                u16* __restrict__ tl, int K, int N){
  __shared__ float t[64][65];
  const int kb = blockIdx.y*64, nb = blockIdx.x*64;
  const int x = threadIdx.x & 63, y = threadIdx.x >> 6;
  for (int yy = y; yy < 64; yy += 4){
    int k = kb + yy, n = nb + x;
    t[yy][x] = (k < K && n < N) ? w[(size_t)k*N + n] : 0.f;
  }
  __syncthreads();
  for (int yy = y; yy < 64; yy += 4){
    int n = nb + yy, k = kb + x;
    if (n < N && k < K){
      float v = t[x][yy];
      u16 hh = f2bf(v);
      th[(size_t)n*K + k] = hh;
      tl[(size_t)n*K + k] = f2bf(v - bf2f(hh));
    }
  }
}

// ---------------- bf16 MFMA GEMM, B^T layout, 128x128 tile, BK=32 ----------------
// NS=1: C=A0*B0^T ; NS=2: split hi/lo 3-term. EPI: 0=none 1=tanh 2=sigmoid 3=dist
template<int NS, int EPI>
__global__ __launch_bounds__(256) void gemm_bt(
    const u16* __restrict__ A0, const u16* __restrict__ A1,
    const u16* __restrict__ B0, const u16* __restrict__ B1,
    const float* __restrict__ bias, const float* __restrict__ sqf,
    float* __restrict__ C, int M, int N, int K)
{
  __shared__ u16 As[NS][128][40];
  __shared__ u16 Bs[NS][128][40];
  const int tid = threadIdx.x;
  const int rowBase = blockIdx.y*128, colBase = blockIdx.x*128;
  const int wid = tid>>6, lane = tid&63;
  const int wr = (wid>>1)*64, wc = (wid&1)*64;
  const int lrow = lane&15, lq = lane>>4;

  f32x4 acc[4][4];
  #pragma unroll
  for (int m=0;m<4;++m)
    #pragma unroll
    for (int n=0;n<4;++n) acc[m][n] = (f32x4){0.f,0.f,0.f,0.f};

  const u16* Ap[2] = {A0, A1};
  const u16* Bp[2] = {B0, B1};

  for (int k0 = 0; k0 < K; k0 += 32){
    #pragma unroll
    for (int s=0; s<NS; ++s){
      #pragma unroll
      for (int p=0;p<2;++p){
        int idx = p*256 + tid;
        int r = idx>>2, c8 = (idx&3)<<3;
        int gk = k0 + c8;
        short8 v = {0,0,0,0,0,0,0,0};
        if (gk < K) v = *(const short8*)(Ap[s] + (size_t)(rowBase+r)*K + gk);
        *(short8*)&As[s][r][c8] = v;
      }
      #pragma unroll
      for (int p=0;p<2;++p){
        int idx = p*256 + tid;
        int r = idx>>2, c8 = (idx&3)<<3;
        int gn = colBase + r, gk = k0 + c8;
        short8 v = {0,0,0,0,0,0,0,0};
        if (gk < K && gn < N) v = *(const short8*)(Bp[s] + (size_t)gn*K + gk);
        *(short8*)&Bs[s][r][c8] = v;
      }
    }
    __syncthreads();
    V8 af[NS][4], bfr[NS][4];
    #pragma unroll
    for (int s=0;s<NS;++s)
      #pragma unroll
      for (int m=0;m<4;++m)
        af[s][m].s = *(const short8*)&As[s][wr + m*16 + lrow][lq<<3];
    #pragma unroll
    for (int s=0;s<NS;++s)
      #pragma unroll
      for (int n=0;n<4;++n)
        bfr[s][n].s = *(const short8*)&Bs[s][wc + n*16 + lrow][lq<<3];
    #pragma unroll
    for (int m=0;m<4;++m)
      #pragma unroll
      for (int n=0;n<4;++n){
        acc[m][n] = __builtin_amdgcn_mfma_f32_16x16x32_bf16(af[0][m].b, bfr[0][n].b, acc[m][n], 0,0,0);
        if (NS == 2){
          acc[m][n] = __builtin_amdgcn_mfma_f32_16x16x32_bf16(af[NS-1][m].b, bfr[0][n].b, acc[m][n], 0,0,0);
          acc[m][n] = __builtin_amdgcn_mfma_f32_16x16x32_bf16(af[0][m].b, bfr[NS-1][n].b, acc[m][n], 0,0,0);
        }
      }
    __syncthreads();
  }

  #pragma unroll
  for (int m=0;m<4;++m)
    #pragma unroll
    for (int n=0;n<4;++n)
      #pragma unroll
      for (int r=0;r<4;++r){
        int row = rowBase + wr + m*16 + lq*4 + r;
        int col = colBase + wc + n*16 + lrow;
        if (col < N){
          float c = acc[m][n][r];
          if (EPI == 3) c = sqf[row] + sqf[col] - 2.0f*c;
          if (bias) c += bias[col];
          if (EPI == 1) c = tanhf(c);
          if (EPI == 2) c = 1.0f/(1.0f + expf(-c));
          C[(size_t)row*N + col] = c;
        }
      }
}

// ---------------- f32 LDS-tiled GEMM (small hpre only) ----------------
template<int EPI>
__global__ __launch_bounds__(256) void sgemm_k(
    const float* __restrict__ A, const float* __restrict__ B,
    const float* __restrict__ bias, float* __restrict__ C, int M, int N, int K)
{
  __shared__ float As[64][17];
  __shared__ float Bs[16][65];
  const int tid = threadIdx.x;
  const int tx = tid & 15, ty = tid >> 4;
  const int rowBase = blockIdx.y*64, colBase = blockIdx.x*64;
  float acc[4][4] = {{0.f}};
  for (int k0 = 0; k0 < K; k0 += 16){
    #pragma unroll
    for (int p = 0; p < 4; ++p){
      int idx = p*256 + tid;
      int r = idx >> 4, kk = idx & 15;
      int gk = k0 + kk;
      As[r][kk] = (gk < K) ? A[(size_t)(rowBase+r)*K + gk] : 0.f;
    }
    #pragma unroll
    for (int p = 0; p < 4; ++p){
      int idx = p*256 + tid;
      int k = idx >> 6, c = idx & 63;
      int gk = k0 + k, gc = colBase + c;
      Bs[k][c] = (gk < K && gc < N) ? B[(size_t)gk*N + gc] : 0.f;
    }
    __syncthreads();
    #pragma unroll
    for (int k = 0; k < 16; ++k){
      float a[4], b[4];
      #pragma unroll
      for (int i=0;i<4;++i) a[i] = As[ty*4+i][k];
      #pragma unroll
      for (int j=0;j<4;++j) b[j] = Bs[k][tx*4+j];
      #pragma unroll
      for (int i=0;i<4;++i)
        #pragma unroll
        for (int j=0;j<4;++j) acc[i][j] = fmaf(a[i], b[j], acc[i][j]);
    }
    __syncthreads();
  }
  #pragma unroll
  for (int i=0;i<4;++i){
    int row = rowBase + ty*4 + i;
    #pragma unroll
    for (int j=0;j<4;++j){
      int col = colBase + tx*4 + j;
      if (col < N){
        float c = acc[i][j];
        if (bias) c += bias[col];
        if (EPI == 1) c = tanhf(c);
        C[(size_t)row*N + col] = c;
      }
    }
  }
}

// ---------------- kNN: f32 top-10 window + margin candidates (cap 96) ----------------
__global__ __launch_bounds__(256) void knn_select(const float* __restrict__ dists,
                                                  int* __restrict__ cand, int* __restrict__ candc){
  const int row = blockIdx.x, tid = threadIdx.x;
  __shared__ float drow[4096];
  __shared__ float rv[256]; __shared__ int ri[256];
  __shared__ float d10s;
  const float* dr = dists + (size_t)row*4096;
  for (int j = tid; j < 4096; j += 256) drow[j] = dr[j];
  __syncthreads();
  for (int t = 0; t < 10; ++t){
    float bv = 3.4e38f; int bi = 0x7FFFFFFF;
    for (int j = tid; j < 4096; j += 256){
      float v = drow[j];
      if (v < bv || (v == bv && j < bi)){ bv = v; bi = j; }
    }
    rv[tid] = bv; ri[tid] = bi;
    __syncthreads();
    for (int s = 128; s > 0; s >>= 1){
      if (tid < s){
        float ov = rv[tid+s]; int oi = ri[tid+s];
        if (ov < rv[tid] || (ov == rv[tid] && oi < ri[tid])){ rv[tid] = ov; ri[tid] = oi; }
      }
      __syncthreads();
    }
    if (tid == 0){ drow[ri[0]] = 3.4e38f; if (t == 9) d10s = rv[0]; }
    __syncthreads();
  }
  const float thr = d10s + 2.0f;
  if (tid < 64){
    int lane = tid;
    int cnt = 0;
    for (int base = 0; base < 4096; base += 64){
      bool p = dr[base+lane] <= thr;
      unsigned long long mask = __ballot(p);
      if (p){
        int pos = __popcll(mask & ((1ull<<lane)-1ull));
        if (cnt + pos < 96) cand[(size_t)row*96 + cnt + pos] = base + lane;
      }
      cnt += __popcll(mask);
    }
    if (lane == 0) candc[row] = cnt < 96 ? cnt : 96;
  }
}

// ---------------- kNN: f32-MIMIC re-rank ----------------
__global__ __launch_bounds__(256) void knn_rank32(const float* __restrict__ x,
    const int* __restrict__ cand, const int* __restrict__ candc,
    int* __restrict__ nbrK, int* __restrict__ nbrKc)
{
  const int row = blockIdx.x, tid = threadIdx.x;
  const int wid = tid>>6, lane = tid&63;
  __shared__ float xi[1024];
  __shared__ float cd[96];
  __shared__ float sqi_sh;
  const float* xr = x + (size_t)row*1024;
  for (int k = tid; k < 1024; k += 256) xi[k] = xr[k];
  __syncthreads();
  if (wid == 0){
    float a = 0.f;
    #pragma unroll
    for (int t = 0; t < 16; ++t){ float v = xi[lane + 64*t]; a = fmaf(v, v, a); }
    a += __shfl_xor(a, 16); a += __shfl_xor(a, 32);
    a += __shfl_xor(a, 8);  a += __shfl_xor(a, 4);
    a += __shfl_xor(a, 2);  a += __shfl_xor(a, 1);
    if (lane == 0) sqi_sh = a;
  }
  __syncthreads();
  const float sqi = sqi_sh;
  const int cnt = candc[row];
  for (int s = wid; s < cnt; s += 4){
    int c = cand[(size_t)row*96 + s];
    const float* xc = x + (size_t)c*1024;
    float ad = 0.f, aq = 0.f;
    #pragma unroll
    for (int t = 0; t < 16; ++t){
      int k = lane + 64*t;
      float v = xc[k];
      ad = fmaf(xi[k], v, ad);
      aq = fmaf(v, v, aq);
    }
    ad += __shfl_xor(ad, 16); ad += __shfl_xor(ad, 32);
    ad += __shfl_xor(ad, 8);  ad += __shfl_xor(ad, 4);
    ad += __shfl_xor(ad, 2);  ad += __shfl_xor(ad, 1);
    aq += __shfl_xor(aq, 16); aq += __shfl_xor(aq, 32);
    aq += __shfl_xor(aq, 8);  aq += __shfl_xor(aq, 4);
    aq += __shfl_xor(aq, 2);  aq += __shfl_xor(aq, 1);
    if (lane == 0) cd[s] = (sqi - 2.0f*ad) + aq;
  }
  __syncthreads();
  if (tid == 0){
    int m = 0;
    int lim = cnt < 10 ? cnt : 10;
    for (int t = 0; t < lim; ++t){
      float bd = 3.4e38f; int bs = 0;
      for (int s = 0; s < cnt; ++s){
        if (cd[s] < bd){ bd = cd[s]; bs = s; }
      }
      cd[bs] = 3.4e38f;
      int j = cand[(size_t)row*96 + bs];
      if (j != row && m < 10){ nbrK[row*10 + m] = j; ++m; }
    }
    nbrKc[row] = m;
  }
}

__global__ __launch_bounds__(64) void scatter_k(const int* __restrict__ nbrK, const int* __restrict__ nbrKc,
                                                float* __restrict__ g){
  int row = blockIdx.x, t = threadIdx.x;
  int m = nbrKc[row];
  if (t < m){
    int j = nbrK[row*10 + t];
    g[(size_t)row*4096 + j] = 1.0f;
    g[(size_t)j*4096 + row] = 1.0f;
  }
}

__global__ __launch_bounds__(64) void build_lists(const float* __restrict__ g, int* __restrict__ nbrl,
                                                  int* __restrict__ nbrc, float* __restrict__ dinv){
  int row = blockIdx.x, lane = threadIdx.x;
  const float* gr = g + (size_t)row*4096;
  int cnt = 0;
  for (int base = 0; base < 4096; base += 64){
    bool p = gr[base+lane] != 0.f;
    unsigned long long mask = __ballot(p);
    if (p){
      int pos = __popcll(mask & ((1ull<<lane)-1ull));
      if (cnt + pos < NBR_CAP) nbrl[(size_t)row*NBR_CAP + cnt + pos] = base + lane;
    }
    cnt += __popcll(mask);
  }
  if (lane == 0){
    nbrc[row] = cnt < NBR_CAP ? cnt : NBR_CAP;
    dinv[row] = 1.0f/sqrtf((float)(cnt + 1));
  }
}

// ---------------- SpMM v2 ----------------
__global__ __launch_bounds__(256) void spmm_k(const float* __restrict__ X, const int* __restrict__ nbrl,
    const int* __restrict__ nbrc, const float* __restrict__ dinv, float* __restrict__ out, int W){
  const int row = blockIdx.y;
  const int lane = threadIdx.x & 63;
  const int sl = threadIdx.x >> 6;
  const int col = blockIdx.x*64 + lane;
  __shared__ int li[NBR_CAP]; __shared__ float lv[NBR_CAP];
  __shared__ float red[4][64];
  const int cnt = nbrc[row];
  for (int t = threadIdx.x; t < cnt; t += 256){
    int j = nbrl[(size_t)row*NBR_CAP + t];
    li[t] = j; lv[t] = dinv[j];
  }
  __syncthreads();
  const float di = dinv[row];
  float p = 0.f;
  if (col < W){
    for (int s = sl; s < cnt; s += 4)
      p = fmaf(lv[s], X[(size_t)li[s]*W + col], p);
    if (sl == 0) p = fmaf(di, X[(size_t)row*W + col], p);
  }
  red[sl][lane] = p;
  __syncthreads();
  if (sl == 0 && col < W){
    float acc = red[0][lane] + red[1][lane] + red[2][lane] + red[3][lane];
    out[(size_t)row*W + col] = di*acc;
  }
}

// ---------------- q = softmax(z @ lc_w + lc_b) ----------------
__global__ __launch_bounds__(64) void q_kernel(const float* __restrict__ z, const float* __restrict__ lcw,
                                               const float* __restrict__ lcb, float* __restrict__ qs){
  int row = blockIdx.x, lane = threadIdx.x;
  __shared__ float ls[10];
  const float* zr = z + (size_t)row*512;
  for (int c = 0; c < 10; ++c){
    float a = 0.f;
    for (int k = lane; k < 512; k += 64) a += zr[k]*lcw[k*10 + c];
    for (int o = 32; o > 0; o >>= 1) a += __shfl_down(a, o);
    if (lane == 0) ls[c] = a + lcb[c];
  }
  __syncthreads();
  if (lane == 0){
    float m = ls[0];
    for (int c = 1; c < 10; ++c) m = fmaxf(m, ls[c]);
    float sum = 0.f, e[10];
    for (int c = 0; c < 10; ++c){ e[c] = expf(ls[c]-m); sum += e[c]; }
    for (int c = 0; c < 10; ++c) qs[(size_t)row*10 + c] = e[c]/sum;
  }
}

// ---------------- h row-normalize ----------------
__global__ __launch_bounds__(64) void hnorm_k(const float* __restrict__ hp, float* __restrict__ hs){
  int row = blockIdx.x, lane = threadIdx.x;
  const float* hr = hp + (size_t)row*128;
  float v0 = hr[lane], v1 = hr[lane+64];
  float a = v0*v0 + v1*v1;
  for (int o = 32; o > 0; o >>= 1) a += __shfl_down(a, o);
  float nrm = sqrtf(__shfl(a, 0));
  hs[(size_t)row*128 + lane]      = v0/nrm;
  hs[(size_t)row*128 + lane + 64] = v1/nrm;
}

extern "C" void kernel_launch(void* const* d_in, const int* in_sizes, int n_in,
                              void* d_out, int out_size, void* d_ws, size_t ws_size,
                              hipStream_t stream)
{
  const float* xs  = (const float*)d_in[0];
  const float* ew1 = (const float*)d_in[1];
  const float* eb1 = (const float*)d_in[2];
  const float* ew2 = (const float*)d_in[3];
  const float* eb2 = (const float*)d_in[4];
  const float* eWp = (const float*)d_in[5];
  const float* dW1 = (const float*)d_in[6];
  const float* dw1 = (const float*)d_in[7];
  const float* db1 = (const float*)d_in[8];
  const float* dw2 = (const float*)d_in[9];
  const float* db2 = (const float*)d_in[10];
  const float* fcw = (const float*)d_in[11];
  const float* fcb = (const float*)d_in[12];
  const float* lcw = (const float*)d_in[13];
  const float* lcb = (const float*)d_in[14];

  float* out = (float*)d_out;
  const size_t HS0 = 0;
  const size_t QS0 = HS0 + (size_t)2*4096*128;
  const size_t XR0 = QS0 + (size_t)2*4096*10;
  const size_t ZS0 = XR0 + (size_t)2*4096*1024;
  const size_t GS0 = ZS0 + (size_t)2*4096*512;
  const size_t AR0 = GS0 + (size_t)2*4096*4096;

  void* sp = nullptr;
  hipGetSymbolAddress(&sp, HIP_SYMBOL(g_scratch));
  if (!sp) return;
  char* ws = (char*)sp;

  // region 0..64MB: dists during graph phase; split buffers afterwards
  float* dists = (float*)(ws + 0);
  u16* GAH = (u16*)(ws + 0);           // 14.75MB (<=4096x1800 A splits)
  u16* GAL = (u16*)(ws + 14745600);
  u16* GWH = (u16*)(ws + 29491200);    // 3.69MB (<=1800x1024 weight^T splits)
  u16* GWL = (u16*)(ws + 33177600);
  u16* ZH  = (u16*)(ws + 36864000);    // 4MB (4096x512)
  u16* ZL  = (u16*)(ws + 41058304);
  u16* WH  = (u16*)(ws + 45252608);
  u16* WL  = (u16*)(ws + 49446912);    // ends 53.6MB < 64MB

  float* o1    = (float*)(ws + 67108864);     // 29.5MB (h11 aliases; XH aliases pre-o1)
  u16* XH = (u16*)(ws + 67108864);            // 8MB (4096x1024) — dists operand (bf16 hi only)
  float* so1   = (float*)(ws + 96600064);     // 29.5MB (sh11 aliases)
  float* sx    = (float*)(ws + 126091264);    // 16MB
  float* sh1   = (float*)(ws + 142868480);    // 8MB
  float* zw    = (float*)(ws + 151257088);    // 8MB
  float* h1    = (float*)(ws + 159645696);    // 8MB
  float* hpre  = (float*)(ws + 168034304);    // 2MB
  float* sqf   = (float*)(ws + 170164224);
  int* cand    = (int*)(ws + 170180608);
  int* candc   = (int*)(ws + 171753472);
  int* nbrK    = (int*)(ws + 171769856);
  int* nbrKc   = (int*)(ws + 171933696);
  int* nbrl    = (int*)(ws + 171950080);      // 32MB
  int* nbrc    = (int*)(ws + 205504512);
  float* dinv  = (float*)(ws + 205520896);
  float* h11   = o1;
  float* sh11  = so1;

  hipMemsetAsync(out + GS0, 0, (size_t)2*4096*4096*sizeof(float), stream);

  for (int v = 0; v < 2; ++v){
    const float* x    = xs  + (size_t)v*4096*1024;
    const float* w1   = ew1 + (size_t)v*1024*1800;
    const float* b1   = eb1 + (size_t)v*1800;
    const float* w2   = ew2 + (size_t)v*1800*512;
    const float* b2   = eb2 + (size_t)v*512;
    const float* We   = eWp + (size_t)v*512*512;
    const float* dWv  = dW1 + (size_t)v*512*512;
    const float* dw1v = dw1 + (size_t)v*512*1800;
    const float* db1v = db1 + (size_t)v*1800;
    const float* dw2v = dw2 + (size_t)v*1800*1024;
    const float* db2v = db2 + (size_t)v*1024;
    float* hs_o = out + HS0 + (size_t)v*4096*128;
    float* qs_o = out + QS0 + (size_t)v*4096*10;
    float* xr_o = out + XR0 + (size_t)v*4096*1024;
    float* zs_o = out + ZS0 + (size_t)v*4096*512;
    float* gs_o = out + GS0 + (size_t)v*4096*4096;
    float* ar_o = out + AR0 + (size_t)v*4096*4096;

    // ---- graph ----
    sq_kernel<<<1024,256,0,stream>>>(x, sqf);
    split_k<<<2048,256,0,stream>>>(x, XH, nullptr, 4096*1024);
    gemm_bt<1,3><<<dim3(32,32),256,0,stream>>>(XH,nullptr,XH,nullptr,nullptr,sqf,dists,4096,4096,1024);
    knn_select<<<4096,256,0,stream>>>(dists, cand, candc);
    knn_rank32<<<4096,256,0,stream>>>(x, cand, candc, nbrK, nbrKc);
    scatter_k<<<4096,64,0,stream>>>(nbrK, nbrKc, gs_o);
    build_lists<<<4096,64,0,stream>>>(gs_o, nbrl, nbrc, dinv);

    // ---- encoder ----
    spmm_k<<<dim3(16,4096),256,0,stream>>>(x, nbrl, nbrc, dinv, sx, 1024);
    split_k<<<2048,256,0,stream>>>(sx, GAH, GAL, 4096*1024);
    tsplit_k<<<dim3(29,16),256,0,stream>>>(w1, GWH, GWL, 1024, 1800);
    gemm_bt<2,1><<<dim3(15,32),256,0,stream>>>(GAH,GAL,GWH,GWL,b1,nullptr,o1,4096,1800,1024);
    spmm_k<<<dim3(29,4096),256,0,stream>>>(o1, nbrl, nbrc, dinv, so1, 1800);
    split_k<<<2048,256,0,stream>>>(so1, GAH, GAL, 4096*1800);
    tsplit_k<<<dim3(8,29),256,0,stream>>>(w2, GWH, GWL, 1800, 512);
    gemm_bt<2,1><<<dim3(4,32),256,0,stream>>>(GAH,GAL,GWH,GWL,b2,nullptr,zs_o,4096,512,1800);

    // ---- a = sigmoid((z@eW)@z^T) ----
    split_k<<<2048,256,0,stream>>>(zs_o, ZH, ZL, 4096*512);
    tsplit_k<<<dim3(8,8),256,0,stream>>>(We, GWH, GWL, 512, 512);
    gemm_bt<2,0><<<dim3(4,32),256,0,stream>>>(ZH,ZL,GWH,GWL,nullptr,nullptr,zw,4096,512,512);
    split_k<<<2048,256,0,stream>>>(zw, WH, WL, 4096*512);
    gemm_bt<2,2><<<dim3(32,32),256,0,stream>>>(WH,WL,ZH,ZL,nullptr,nullptr,ar_o,4096,4096,512);

    // ---- heads ----
    sgemm_k<0><<<dim3(2,64),256,0,stream>>>(zs_o,fcw,fcb,hpre,4096,128,512);
    hnorm_k<<<4096,64,0,stream>>>(hpre, hs_o);
    q_kernel<<<4096,64,0,stream>>>(zs_o, lcw, lcb, qs_o);

    // ---- decoder ----
    tsplit_k<<<dim3(8,8),256,0,stream>>>(dWv, GWH, GWL, 512, 512);
    gemm_bt<2,1><<<dim3(4,32),256,0,stream>>>(ZH,ZL,GWH,GWL,nullptr,nullptr,h1,4096,512,512);
    spmm_k<<<dim3(8,4096),256,0,stream>>>(h1, nbrl, nbrc, dinv, sh1, 512);
    split_k<<<2048,256,0,stream>>>(sh1, GAH, GAL, 4096*512);
    tsplit_k<<<dim3(29,8),256,0,stream>>>(dw1v, GWH, GWL, 512, 1800);
    gemm_bt<2,1><<<dim3(15,32),256,0,stream>>>(GAH,GAL,GWH,GWL,db1v,nullptr,h11,4096,1800,512);
    spmm_k<<<dim3(29,4096),256,0,stream>>>(h11, nbrl, nbrc, dinv, sh11, 1800);
    split_k<<<2048,256,0,stream>>>(sh11, GAH, GAL, 4096*1800);
    tsplit_k<<<dim3(16,29),256,0,stream>>>(dw2v, GWH, GWL, 1800, 1024);
    gemm_bt<2,1><<<dim3(8,32),256,0,stream>>>(GAH,GAL,GWH,GWL,db2v,nullptr,xr_o,4096,1024,1800);
  }
}

// Round 15
// 3001.473 us; speedup vs baseline: 3.4650x; 1.1166x over previous
//
#include <hip/hip_runtime.h>
#include <math.h>
#include <stdint.h>

typedef uint16_t u16;
typedef __attribute__((ext_vector_type(8))) short short8;
typedef __attribute__((ext_vector_type(8))) __bf16 bf16x8;
typedef __attribute__((ext_vector_type(4))) float f32x4;
union V8 { short8 s; bf16x8 b; };

__device__ __align__(256) char g_scratch[234881024];  // 224 MB

#define NBR_CAP 2048

__device__ inline float bf2f(u16 u){ return __uint_as_float(((uint32_t)u)<<16); }
__device__ inline u16 f2bf(float f){
  uint32_t x = __float_as_uint(f);
  uint32_t r = (x + 0x7FFFu + ((x>>16)&1u)) >> 16;
  return (u16)r;
}

// ---------------- zero fill (float4) ----------------
__global__ __launch_bounds__(256) void zero_k(f32x4* __restrict__ p, size_t n4){
  size_t i = (size_t)blockIdx.x*256 + threadIdx.x;
  size_t stride = (size_t)gridDim.x*256;
  f32x4 z = {0.f,0.f,0.f,0.f};
  for (; i < n4; i += stride) p[i] = z;
}

// ---------------- sq ----------------
__global__ __launch_bounds__(256) void sq_kernel(const float* __restrict__ x,
                                                 float* __restrict__ sqf){
  int wid = threadIdx.x >> 6, lane = threadIdx.x & 63;
  int row = blockIdx.x*4 + wid;
  const float* xr = x + (size_t)row*1024;
  double acc = 0.0;
  for (int k = lane; k < 1024; k += 64){ float v = xr[k]; acc += (double)v*(double)v; }
  for (int o = 32; o > 0; o >>= 1) acc += __shfl_down(acc, o);
  if (lane == 0) sqf[row] = (float)acc;
}

// ---------------- split f32 -> bf16 hi (+ optional lo) ----------------
__global__ __launch_bounds__(256) void split_k(const float* __restrict__ x, u16* __restrict__ h,
                                               u16* __restrict__ l, int n){
  int i = blockIdx.x*256 + threadIdx.x;
  int stride = gridDim.x*256;
  for (; i < n; i += stride){
    float v = x[i];
    u16 hh = f2bf(v);
    h[i] = hh;
    if (l) l[i] = f2bf(v - bf2f(hh));
  }
}

// ---------------- transpose + split: w[K][N] -> th/tl [N][K] ----------------
__global__ __launch_bounds__(256) void tsplit_k(const float* __restrict__ w, u16* __restrict__ th,
                                                u16* __restrict__ tl, int K, int N){
  __shared__ float t[64][65];
  const int kb = blockIdx.y*64, nb = blockIdx.x*64;
  const int x = threadIdx.x & 63, y = threadIdx.x >> 6;
  for (int yy = y; yy < 64; yy += 4){
    int k = kb + yy, n = nb + x;
    t[yy][x] = (k < K && n < N) ? w[(size_t)k*N + n] : 0.f;
  }
  __syncthreads();
  for (int yy = y; yy < 64; yy += 4){
    int n = nb + yy, k = kb + x;
    if (n < N && k < K){
      float v = t[x][yy];
      u16 hh = f2bf(v);
      th[(size_t)n*K + k] = hh;
      tl[(size_t)n*K + k] = f2bf(v - bf2f(hh));
    }
  }
}

// ---------------- bf16 MFMA GEMM, B^T layout, 128x128 tile, BK=32 ----------------
// NS=1: C=A0*B0^T ; NS=2: split hi/lo 3-term. EPI: 0=none 1=tanh 2=sigmoid 3=dist
template<int NS, int EPI>
__global__ __launch_bounds__(256) void gemm_bt(
    const u16* __restrict__ A0, const u16* __restrict__ A1,
    const u16* __restrict__ B0, const u16* __restrict__ B1,
    const float* __restrict__ bias, const float* __restrict__ sqf,
    float* __restrict__ C, int M, int N, int K)
{
  __shared__ u16 As[NS][128][40];
  __shared__ u16 Bs[NS][128][40];
  const int tid = threadIdx.x;
  const int rowBase = blockIdx.y*128, colBase = blockIdx.x*128;
  const int wid = tid>>6, lane = tid&63;
  const int wr = (wid>>1)*64, wc = (wid&1)*64;
  const int lrow = lane&15, lq = lane>>4;

  f32x4 acc[4][4];
  #pragma unroll
  for (int m=0;m<4;++m)
    #pragma unroll
    for (int n=0;n<4;++n) acc[m][n] = (f32x4){0.f,0.f,0.f,0.f};

  const u16* Ap[2] = {A0, A1};
  const u16* Bp[2] = {B0, B1};

  for (int k0 = 0; k0 < K; k0 += 32){
    #pragma unroll
    for (int s=0; s<NS; ++s){
      #pragma unroll
      for (int p=0;p<2;++p){
        int idx = p*256 + tid;
        int r = idx>>2, c8 = (idx&3)<<3;
        int gk = k0 + c8;
        short8 v = {0,0,0,0,0,0,0,0};
        if (gk < K) v = *(const short8*)(Ap[s] + (size_t)(rowBase+r)*K + gk);
        *(short8*)&As[s][r][c8] = v;
      }
      #pragma unroll
      for (int p=0;p<2;++p){
        int idx = p*256 + tid;
        int r = idx>>2, c8 = (idx&3)<<3;
        int gn = colBase + r, gk = k0 + c8;
        short8 v = {0,0,0,0,0,0,0,0};
        if (gk < K && gn < N) v = *(const short8*)(Bp[s] + (size_t)gn*K + gk);
        *(short8*)&Bs[s][r][c8] = v;
      }
    }
    __syncthreads();
    V8 af[NS][4], bfr[NS][4];
    #pragma unroll
    for (int s=0;s<NS;++s)
      #pragma unroll
      for (int m=0;m<4;++m)
        af[s][m].s = *(const short8*)&As[s][wr + m*16 + lrow][lq<<3];
    #pragma unroll
    for (int s=0;s<NS;++s)
      #pragma unroll
      for (int n=0;n<4;++n)
        bfr[s][n].s = *(const short8*)&Bs[s][wc + n*16 + lrow][lq<<3];
    #pragma unroll
    for (int m=0;m<4;++m)
      #pragma unroll
      for (int n=0;n<4;++n){
        acc[m][n] = __builtin_amdgcn_mfma_f32_16x16x32_bf16(af[0][m].b, bfr[0][n].b, acc[m][n], 0,0,0);
        if (NS == 2){
          acc[m][n] = __builtin_amdgcn_mfma_f32_16x16x32_bf16(af[NS-1][m].b, bfr[0][n].b, acc[m][n], 0,0,0);
          acc[m][n] = __builtin_amdgcn_mfma_f32_16x16x32_bf16(af[0][m].b, bfr[NS-1][n].b, acc[m][n], 0,0,0);
        }
      }
    __syncthreads();
  }

  #pragma unroll
  for (int m=0;m<4;++m)
    #pragma unroll
    for (int n=0;n<4;++n)
      #pragma unroll
      for (int r=0;r<4;++r){
        int row = rowBase + wr + m*16 + lq*4 + r;
        int col = colBase + wc + n*16 + lrow;
        if (col < N){
          float c = acc[m][n][r];
          if (EPI == 3) c = sqf[row] + sqf[col] - 2.0f*c;
          if (bias) c += bias[col];
          if (EPI == 1) c = tanhf(c);
          if (EPI == 2) c = 1.0f/(1.0f + expf(-c));
          C[(size_t)row*N + col] = c;
        }
      }
}

// ---------------- f32 LDS-tiled GEMM (small hpre only) ----------------
template<int EPI>
__global__ __launch_bounds__(256) void sgemm_k(
    const float* __restrict__ A, const float* __restrict__ B,
    const float* __restrict__ bias, float* __restrict__ C, int M, int N, int K)
{
  __shared__ float As[64][17];
  __shared__ float Bs[16][65];
  const int tid = threadIdx.x;
  const int tx = tid & 15, ty = tid >> 4;
  const int rowBase = blockIdx.y*64, colBase = blockIdx.x*64;
  float acc[4][4] = {{0.f}};
  for (int k0 = 0; k0 < K; k0 += 16){
    #pragma unroll
    for (int p = 0; p < 4; ++p){
      int idx = p*256 + tid;
      int r = idx >> 4, kk = idx & 15;
      int gk = k0 + kk;
      As[r][kk] = (gk < K) ? A[(size_t)(rowBase+r)*K + gk] : 0.f;
    }
    #pragma unroll
    for (int p = 0; p < 4; ++p){
      int idx = p*256 + tid;
      int k = idx >> 6, c = idx & 63;
      int gk = k0 + k, gc = colBase + c;
      Bs[k][c] = (gk < K && gc < N) ? B[(size_t)gk*N + gc] : 0.f;
    }
    __syncthreads();
    #pragma unroll
    for (int k = 0; k < 16; ++k){
      float a[4], b[4];
      #pragma unroll
      for (int i=0;i<4;++i) a[i] = As[ty*4+i][k];
      #pragma unroll
      for (int j=0;j<4;++j) b[j] = Bs[k][tx*4+j];
      #pragma unroll
      for (int i=0;i<4;++i)
        #pragma unroll
        for (int j=0;j<4;++j) acc[i][j] = fmaf(a[i], b[j], acc[i][j]);
    }
    __syncthreads();
  }
  #pragma unroll
  for (int i=0;i<4;++i){
    int row = rowBase + ty*4 + i;
    #pragma unroll
    for (int j=0;j<4;++j){
      int col = colBase + tx*4 + j;
      if (col < N){
        float c = acc[i][j];
        if (bias) c += bias[col];
        if (EPI == 1) c = tanhf(c);
        C[(size_t)row*N + col] = c;
      }
    }
  }
}

// ---------------- kNN: f32 top-10 window + margin candidates (cap 96) ----------------
__global__ __launch_bounds__(256) void knn_select(const float* __restrict__ dists,
                                                  int* __restrict__ cand, int* __restrict__ candc){
  const int row = blockIdx.x, tid = threadIdx.x;
  __shared__ float drow[4096];
  __shared__ float rv[256]; __shared__ int ri[256];
  __shared__ float d10s;
  const float* dr = dists + (size_t)row*4096;
  for (int j = tid; j < 4096; j += 256) drow[j] = dr[j];
  __syncthreads();
  for (int t = 0; t < 10; ++t){
    float bv = 3.4e38f; int bi = 0x7FFFFFFF;
    for (int j = tid; j < 4096; j += 256){
      float v = drow[j];
      if (v < bv || (v == bv && j < bi)){ bv = v; bi = j; }
    }
    rv[tid] = bv; ri[tid] = bi;
    __syncthreads();
    for (int s = 128; s > 0; s >>= 1){
      if (tid < s){
        float ov = rv[tid+s]; int oi = ri[tid+s];
        if (ov < rv[tid] || (ov == rv[tid] && oi < ri[tid])){ rv[tid] = ov; ri[tid] = oi; }
      }
      __syncthreads();
    }
    if (tid == 0){ drow[ri[0]] = 3.4e38f; if (t == 9) d10s = rv[0]; }
    __syncthreads();
  }
  const float thr = d10s + 2.0f;
  if (tid < 64){
    int lane = tid;
    int cnt = 0;
    for (int base = 0; base < 4096; base += 64){
      bool p = dr[base+lane] <= thr;
      unsigned long long mask = __ballot(p);
      if (p){
        int pos = __popcll(mask & ((1ull<<lane)-1ull));
        if (cnt + pos < 96) cand[(size_t)row*96 + cnt + pos] = base + lane;
      }
      cnt += __popcll(mask);
    }
    if (lane == 0) candc[row] = cnt < 96 ? cnt : 96;
  }
}

// ---------------- kNN: f32-MIMIC re-rank ----------------
__global__ __launch_bounds__(256) void knn_rank32(const float* __restrict__ x,
    const int* __restrict__ cand, const int* __restrict__ candc,
    int* __restrict__ nbrK, int* __restrict__ nbrKc)
{
  const int row = blockIdx.x, tid = threadIdx.x;
  const int wid = tid>>6, lane = tid&63;
  __shared__ float xi[1024];
  __shared__ float cd[96];
  __shared__ float sqi_sh;
  const float* xr = x + (size_t)row*1024;
  for (int k = tid; k < 1024; k += 256) xi[k] = xr[k];
  __syncthreads();
  if (wid == 0){
    float a = 0.f;
    #pragma unroll
    for (int t = 0; t < 16; ++t){ float v = xi[lane + 64*t]; a = fmaf(v, v, a); }
    a += __shfl_xor(a, 16); a += __shfl_xor(a, 32);
    a += __shfl_xor(a, 8);  a += __shfl_xor(a, 4);
    a += __shfl_xor(a, 2);  a += __shfl_xor(a, 1);
    if (lane == 0) sqi_sh = a;
  }
  __syncthreads();
  const float sqi = sqi_sh;
  const int cnt = candc[row];
  for (int s = wid; s < cnt; s += 4){
    int c = cand[(size_t)row*96 + s];
    const float* xc = x + (size_t)c*1024;
    float ad = 0.f, aq = 0.f;
    #pragma unroll
    for (int t = 0; t < 16; ++t){
      int k = lane + 64*t;
      float v = xc[k];
      ad = fmaf(xi[k], v, ad);
      aq = fmaf(v, v, aq);
    }
    ad += __shfl_xor(ad, 16); ad += __shfl_xor(ad, 32);
    ad += __shfl_xor(ad, 8);  ad += __shfl_xor(ad, 4);
    ad += __shfl_xor(ad, 2);  ad += __shfl_xor(ad, 1);
    aq += __shfl_xor(aq, 16); aq += __shfl_xor(aq, 32);
    aq += __shfl_xor(aq, 8);  aq += __shfl_xor(aq, 4);
    aq += __shfl_xor(aq, 2);  aq += __shfl_xor(aq, 1);
    if (lane == 0) cd[s] = (sqi - 2.0f*ad) + aq;
  }
  __syncthreads();
  if (tid == 0){
    int m = 0;
    int lim = cnt < 10 ? cnt : 10;
    for (int t = 0; t < lim; ++t){
      float bd = 3.4e38f; int bs = 0;
      for (int s = 0; s < cnt; ++s){
        if (cd[s] < bd){ bd = cd[s]; bs = s; }
      }
      cd[bs] = 3.4e38f;
      int j = cand[(size_t)row*96 + bs];
      if (j != row && m < 10){ nbrK[row*10 + m] = j; ++m; }
    }
    nbrKc[row] = m;
  }
}

__global__ __launch_bounds__(64) void scatter_k(const int* __restrict__ nbrK, const int* __restrict__ nbrKc,
                                                float* __restrict__ g){
  int row = blockIdx.x, t = threadIdx.x;
  int m = nbrKc[row];
  if (t < m){
    int j = nbrK[row*10 + t];
    g[(size_t)row*4096 + j] = 1.0f;
    g[(size_t)j*4096 + row] = 1.0f;
  }
}

__global__ __launch_bounds__(64) void build_lists(const float* __restrict__ g, int* __restrict__ nbrl,
                                                  int* __restrict__ nbrc, float* __restrict__ dinv){
  int row = blockIdx.x, lane = threadIdx.x;
  const float* gr = g + (size_t)row*4096;
  int cnt = 0;
  for (int base = 0; base < 4096; base += 64){
    bool p = gr[base+lane] != 0.f;
    unsigned long long mask = __ballot(p);
    if (p){
      int pos = __popcll(mask & ((1ull<<lane)-1ull));
      if (cnt + pos < NBR_CAP) nbrl[(size_t)row*NBR_CAP + cnt + pos] = base + lane;
    }
    cnt += __popcll(mask);
  }
  if (lane == 0){
    nbrc[row] = cnt < NBR_CAP ? cnt : NBR_CAP;
    dinv[row] = 1.0f/sqrtf((float)(cnt + 1));
  }
}

// ---------------- SpMM v3: float4 per thread, 256 cols/block ----------------
__global__ __launch_bounds__(256) void spmm_k(const float* __restrict__ X, const int* __restrict__ nbrl,
    const int* __restrict__ nbrc, const float* __restrict__ dinv, float* __restrict__ out, int W){
  const int row = blockIdx.y;
  const int lane = threadIdx.x & 63;
  const int sl = threadIdx.x >> 6;
  const int col4 = blockIdx.x*256 + lane*4;
  __shared__ int li[NBR_CAP]; __shared__ float lv[NBR_CAP];
  __shared__ f32x4 red[4][64];
  const int cnt = nbrc[row];
  for (int t = threadIdx.x; t < cnt; t += 256){
    int j = nbrl[(size_t)row*NBR_CAP + t];
    li[t] = j; lv[t] = dinv[j];
  }
  __syncthreads();
  const float di = dinv[row];
  f32x4 p = {0.f,0.f,0.f,0.f};
  if (col4 + 3 < W){
    for (int s = sl; s < cnt; s += 4){
      f32x4 xv = *(const f32x4*)(X + (size_t)li[s]*W + col4);
      p += lv[s]*xv;
    }
    if (sl == 0){
      f32x4 xv = *(const f32x4*)(X + (size_t)row*W + col4);
      p += di*xv;
    }
  } else if (col4 < W){
    #pragma unroll
    for (int e = 0; e < 4; ++e){
      int c = col4 + e;
      if (c < W){
        float a = 0.f;
        for (int s = sl; s < cnt; s += 4) a = fmaf(lv[s], X[(size_t)li[s]*W + c], a);
        if (sl == 0) a = fmaf(di, X[(size_t)row*W + c], a);
        p[e] = a;
      }
    }
  }
  red[sl][lane] = p;
  __syncthreads();
  if (sl == 0 && col4 < W){
    f32x4 acc = red[0][lane] + red[1][lane] + red[2][lane] + red[3][lane];
    acc = di*acc;
    #pragma unroll
    for (int e = 0; e < 4; ++e){
      int c = col4 + e;
      if (c < W) out[(size_t)row*W + c] = acc[e];
    }
  }
}

// ---------------- q = softmax(z @ lc_w + lc_b) ----------------
__global__ __launch_bounds__(64) void q_kernel(const float* __restrict__ z, const float* __restrict__ lcw,
                                               const float* __restrict__ lcb, float* __restrict__ qs){
  int row = blockIdx.x, lane = threadIdx.x;
  __shared__ float ls[10];
  const float* zr = z + (size_t)row*512;
  for (int c = 0; c < 10; ++c){
    float a = 0.f;
    for (int k = lane; k < 512; k += 64) a += zr[k]*lcw[k*10 + c];
    for (int o = 32; o > 0; o >>= 1) a += __shfl_down(a, o);
    if (lane == 0) ls[c] = a + lcb[c];
  }
  __syncthreads();
  if (lane == 0){
    float m = ls[0];
    for (int c = 1; c < 10; ++c) m = fmaxf(m, ls[c]);
    float sum = 0.f, e[10];
    for (int c = 0; c < 10; ++c){ e[c] = expf(ls[c]-m); sum += e[c]; }
    for (int c = 0; c < 10; ++c) qs[(size_t)row*10 + c] = e[c]/sum;
  }
}

// ---------------- h row-normalize ----------------
__global__ __launch_bounds__(64) void hnorm_k(const float* __restrict__ hp, float* __restrict__ hs){
  int row = blockIdx.x, lane = threadIdx.x;
  const float* hr = hp + (size_t)row*128;
  float v0 = hr[lane], v1 = hr[lane+64];
  float a = v0*v0 + v1*v1;
  for (int o = 32; o > 0; o >>= 1) a += __shfl_down(a, o);
  float nrm = sqrtf(__shfl(a, 0));
  hs[(size_t)row*128 + lane]      = v0/nrm;
  hs[(size_t)row*128 + lane + 64] = v1/nrm;
}

extern "C" void kernel_launch(void* const* d_in, const int* in_sizes, int n_in,
                              void* d_out, int out_size, void* d_ws, size_t ws_size,
                              hipStream_t stream)
{
  const float* xs  = (const float*)d_in[0];
  const float* ew1 = (const float*)d_in[1];
  const float* eb1 = (const float*)d_in[2];
  const float* ew2 = (const float*)d_in[3];
  const float* eb2 = (const float*)d_in[4];
  const float* eWp = (const float*)d_in[5];
  const float* dW1 = (const float*)d_in[6];
  const float* dw1 = (const float*)d_in[7];
  const float* db1 = (const float*)d_in[8];
  const float* dw2 = (const float*)d_in[9];
  const float* db2 = (const float*)d_in[10];
  const float* fcw = (const float*)d_in[11];
  const float* fcb = (const float*)d_in[12];
  const float* lcw = (const float*)d_in[13];
  const float* lcb = (const float*)d_in[14];

  float* out = (float*)d_out;
  const size_t HS0 = 0;
  const size_t QS0 = HS0 + (size_t)2*4096*128;
  const size_t XR0 = QS0 + (size_t)2*4096*10;
  const size_t ZS0 = XR0 + (size_t)2*4096*1024;
  const size_t GS0 = ZS0 + (size_t)2*4096*512;
  const size_t AR0 = GS0 + (size_t)2*4096*4096;

  void* sp = nullptr;
  hipGetSymbolAddress(&sp, HIP_SYMBOL(g_scratch));
  if (!sp) return;
  char* ws = (char*)sp;

  // region 0..64MB: dists during graph phase; split buffers afterwards
  float* dists = (float*)(ws + 0);
  u16* GAH = (u16*)(ws + 0);           // 14.75MB (<=4096x1800 A splits)
  u16* GAL = (u16*)(ws + 14745600);
  u16* GWH = (u16*)(ws + 29491200);    // 3.69MB (<=1800x1024 weight^T splits)
  u16* GWL = (u16*)(ws + 33177600);
  u16* ZH  = (u16*)(ws + 36864000);    // 4MB (4096x512)
  u16* ZL  = (u16*)(ws + 41058304);
  u16* WH  = (u16*)(ws + 45252608);
  u16* WL  = (u16*)(ws + 49446912);    // ends 53.6MB < 64MB

  float* o1    = (float*)(ws + 67108864);     // 29.5MB (h11 aliases; XH aliases pre-o1)
  u16* XH = (u16*)(ws + 67108864);            // 8MB (4096x1024) — dists operand (bf16 hi only)
  float* so1   = (float*)(ws + 96600064);     // 29.5MB (sh11 aliases)
  float* sx    = (float*)(ws + 126091264);    // 16MB
  float* sh1   = (float*)(ws + 142868480);    // 8MB
  float* zw    = (float*)(ws + 151257088);    // 8MB
  float* h1    = (float*)(ws + 159645696);    // 8MB
  float* hpre  = (float*)(ws + 168034304);    // 2MB
  float* sqf   = (float*)(ws + 170164224);
  int* cand    = (int*)(ws + 170180608);
  int* candc   = (int*)(ws + 171753472);
  int* nbrK    = (int*)(ws + 171769856);
  int* nbrKc   = (int*)(ws + 171933696);
  int* nbrl    = (int*)(ws + 171950080);      // 32MB
  int* nbrc    = (int*)(ws + 205504512);
  float* dinv  = (float*)(ws + 205520896);
  float* h11   = o1;
  float* sh11  = so1;

  zero_k<<<2048,256,0,stream>>>((f32x4*)(out + GS0), (size_t)2*4096*4096/4);

  for (int v = 0; v < 2; ++v){
    const float* x    = xs  + (size_t)v*4096*1024;
    const float* w1   = ew1 + (size_t)v*1024*1800;
    const float* b1   = eb1 + (size_t)v*1800;
    const float* w2   = ew2 + (size_t)v*1800*512;
    const float* b2   = eb2 + (size_t)v*512;
    const float* We   = eWp + (size_t)v*512*512;
    const float* dWv  = dW1 + (size_t)v*512*512;
    const float* dw1v = dw1 + (size_t)v*512*1800;
    const float* db1v = db1 + (size_t)v*1800;
    const float* dw2v = dw2 + (size_t)v*1800*1024;
    const float* db2v = db2 + (size_t)v*1024;
    float* hs_o = out + HS0 + (size_t)v*4096*128;
    float* qs_o = out + QS0 + (size_t)v*4096*10;
    float* xr_o = out + XR0 + (size_t)v*4096*1024;
    float* zs_o = out + ZS0 + (size_t)v*4096*512;
    float* gs_o = out + GS0 + (size_t)v*4096*4096;
    float* ar_o = out + AR0 + (size_t)v*4096*4096;

    // ---- graph ----
    sq_kernel<<<1024,256,0,stream>>>(x, sqf);
    split_k<<<2048,256,0,stream>>>(x, XH, nullptr, 4096*1024);
    gemm_bt<1,3><<<dim3(32,32),256,0,stream>>>(XH,nullptr,XH,nullptr,nullptr,sqf,dists,4096,4096,1024);
    knn_select<<<4096,256,0,stream>>>(dists, cand, candc);
    knn_rank32<<<4096,256,0,stream>>>(x, cand, candc, nbrK, nbrKc);
    scatter_k<<<4096,64,0,stream>>>(nbrK, nbrKc, gs_o);
    build_lists<<<4096,64,0,stream>>>(gs_o, nbrl, nbrc, dinv);

    // ---- encoder ----
    spmm_k<<<dim3(4,4096),256,0,stream>>>(x, nbrl, nbrc, dinv, sx, 1024);
    split_k<<<2048,256,0,stream>>>(sx, GAH, GAL, 4096*1024);
    tsplit_k<<<dim3(29,16),256,0,stream>>>(w1, GWH, GWL, 1024, 1800);
    gemm_bt<2,1><<<dim3(15,32),256,0,stream>>>(GAH,GAL,GWH,GWL,b1,nullptr,o1,4096,1800,1024);
    spmm_k<<<dim3(8,4096),256,0,stream>>>(o1, nbrl, nbrc, dinv, so1, 1800);
    split_k<<<2048,256,0,stream>>>(so1, GAH, GAL, 4096*1800);
    tsplit_k<<<dim3(8,29),256,0,stream>>>(w2, GWH, GWL, 1800, 512);
    gemm_bt<2,1><<<dim3(4,32),256,0,stream>>>(GAH,GAL,GWH,GWL,b2,nullptr,zs_o,4096,512,1800);

    // ---- a = sigmoid((z@eW)@z^T) ----
    split_k<<<2048,256,0,stream>>>(zs_o, ZH, ZL, 4096*512);
    tsplit_k<<<dim3(8,8),256,0,stream>>>(We, GWH, GWL, 512, 512);
    gemm_bt<2,0><<<dim3(4,32),256,0,stream>>>(ZH,ZL,GWH,GWL,nullptr,nullptr,zw,4096,512,512);
    split_k<<<2048,256,0,stream>>>(zw, WH, WL, 4096*512);
    gemm_bt<2,2><<<dim3(32,32),256,0,stream>>>(WH,WL,ZH,ZL,nullptr,nullptr,ar_o,4096,4096,512);

    // ---- heads ----
    sgemm_k<0><<<dim3(2,64),256,0,stream>>>(zs_o,fcw,fcb,hpre,4096,128,512);
    hnorm_k<<<4096,64,0,stream>>>(hpre, hs_o);
    q_kernel<<<4096,64,0,stream>>>(zs_o, lcw, lcb, qs_o);

    // ---- decoder ----
    tsplit_k<<<dim3(8,8),256,0,stream>>>(dWv, GWH, GWL, 512, 512);
    gemm_bt<2,1><<<dim3(4,32),256,0,stream>>>(ZH,ZL,GWH,GWL,nullptr,nullptr,h1,4096,512,512);
    spmm_k<<<dim3(2,4096),256,0,stream>>>(h1, nbrl, nbrc, dinv, sh1, 512);
    split_k<<<2048,256,0,stream>>>(sh1, GAH, GAL, 4096*512);
    tsplit_k<<<dim3(29,8),256,0,stream>>>(dw1v, GWH, GWL, 512, 1800);
    gemm_bt<2,1><<<dim3(15,32),256,0,stream>>>(GAH,GAL,GWH,GWL,db1v,nullptr,h11,4096,1800,512);
    spmm_k<<<dim3(8,4096),256,0,stream>>>(h11, nbrl, nbrc, dinv, sh11, 1800);
    split_k<<<2048,256,0,stream>>>(sh11, GAH, GAL, 4096*1800);
    tsplit_k<<<dim3(16,29),256,0,stream>>>(dw2v, GWH, GWL, 1800, 1024);
    gemm_bt<2,1><<<dim3(8,32),256,0,stream>>>(GAH,GAL,GWH,GWL,db2v,nullptr,xr_o,4096,1024,1800);
  }
}

// Round 16
// 2568.103 us; speedup vs baseline: 4.0497x; 1.1688x over previous
//
#include <hip/hip_runtime.h>
#include <math.h>
#include <stdint.h>

typedef uint16_t u16;
typedef __attribute__((ext_vector_type(8))) short short8;
typedef __attribute__((ext_vector_type(8))) __bf16 bf16x8;
typedef __attribute__((ext_vector_type(4))) float f32x4;
union V8 { short8 s; bf16x8 b; };

__device__ __align__(256) char g_scratch[234881024];  // 224 MB

#define NBR_CAP 2048

__device__ inline float bf2f(u16 u){ return __uint_as_float(((uint32_t)u)<<16); }
__device__ inline u16 f2bf(float f){
  uint32_t x = __float_as_uint(f);
  uint32_t r = (x + 0x7FFFu + ((x>>16)&1u)) >> 16;
  return (u16)r;
}

__device__ inline void gload16(const u16* g, u16* l){
  __builtin_amdgcn_global_load_lds((const __attribute__((address_space(1))) uint32_t*)g,
                                   (__attribute__((address_space(3))) uint32_t*)l, 16, 0, 0);
}

// ---------------- zero fill (float4) ----------------
__global__ __launch_bounds__(256) void zero_k(f32x4* __restrict__ p, size_t n4){
  size_t i = (size_t)blockIdx.x*256 + threadIdx.x;
  size_t stride = (size_t)gridDim.x*256;
  f32x4 z = {0.f,0.f,0.f,0.f};
  for (; i < n4; i += stride) p[i] = z;
}

// ---------------- sq ----------------
__global__ __launch_bounds__(256) void sq_kernel(const float* __restrict__ x,
                                                 float* __restrict__ sqf){
  int wid = threadIdx.x >> 6, lane = threadIdx.x & 63;
  int row = blockIdx.x*4 + wid;
  const float* xr = x + (size_t)row*1024;
  double acc = 0.0;
  for (int k = lane; k < 1024; k += 64){ float v = xr[k]; acc += (double)v*(double)v; }
  for (int o = 32; o > 0; o >>= 1) acc += __shfl_down(acc, o);
  if (lane == 0) sqf[row] = (float)acc;
}

// ---------------- split with K padding: x[4096][K] -> h/l [4096][Kp] ----------------
__global__ __launch_bounds__(256) void split_pad(const float* __restrict__ x, u16* __restrict__ h,
                                                 u16* __restrict__ l, int K, int Kp){
  int row = blockIdx.y;
  int c = blockIdx.x*256 + threadIdx.x;
  if (c >= Kp) return;
  float v = (c < K) ? x[(size_t)row*K + c] : 0.f;
  u16 hh = f2bf(v);
  h[(size_t)row*Kp + c] = hh;
  if (l) l[(size_t)row*Kp + c] = f2bf(v - bf2f(hh));
}

// ---------------- transpose + split + pad: w[K][N] -> th/tl [Npad][Kp] ----------------
__global__ __launch_bounds__(256) void tsplit_pad(const float* __restrict__ w, u16* __restrict__ th,
                                                  u16* __restrict__ tl, int K, int N, int Kp, int Npad){
  __shared__ float t[64][65];
  const int kb = blockIdx.y*64, nb = blockIdx.x*64;
  const int x = threadIdx.x & 63, y = threadIdx.x >> 6;
  for (int yy = y; yy < 64; yy += 4){
    int k = kb + yy, n = nb + x;
    t[yy][x] = (k < K && n < N) ? w[(size_t)k*N + n] : 0.f;
  }
  __syncthreads();
  for (int yy = y; yy < 64; yy += 4){
    int n = nb + yy, k = kb + x;
    if (n < Npad && k < Kp){
      float v = t[x][yy];
      u16 hh = f2bf(v);
      th[(size_t)n*Kp + k] = hh;
      tl[(size_t)n*Kp + k] = f2bf(v - bf2f(hh));
    }
  }
}

// ---------------- bf16 MFMA GEMM, B^T, 128x128 tile, BK=32, global_load_lds staging ----------------
// LDS linear [128][32] u16 per part; 16B-chunk XOR swizzle (c16 ^= row&3) applied on
// pre-swizzled global source and on ds_read. Kp must be a multiple of 32; buffers padded.
// NS=1: C=A0*B0^T ; NS=2: split hi/lo 3-term. EPI: 0=none 1=tanh 2=sigmoid 3=dist
template<int NS, int EPI>
__global__ __launch_bounds__(256) void gemm_bt(
    const u16* __restrict__ A0, const u16* __restrict__ A1,
    const u16* __restrict__ B0, const u16* __restrict__ B1,
    const float* __restrict__ bias, const float* __restrict__ sqf,
    float* __restrict__ C, int M, int N, int Kp)
{
  __shared__ u16 As[NS][128][32];
  __shared__ u16 Bs[NS][128][32];
  const int tid = threadIdx.x;
  const int rowBase = blockIdx.y*128, colBase = blockIdx.x*128;
  const int wid = tid>>6, lane = tid&63;
  const int wr = (wid>>1)*64, wc = (wid&1)*64;
  const int lrow = lane&15, lq = lane>>4;

  // staging slots: slot = p*256 + tid -> row = slot>>2, stored chunk c16s = slot&3,
  // global chunk c16g = c16s ^ (row&3)  (source pre-swizzle)
  int srow[2], scol[2];
  #pragma unroll
  for (int p=0;p<2;++p){
    int slot = p*256 + tid;
    srow[p] = slot>>2;
    scol[p] = (slot&3) ^ (srow[p]&3);
  }
  const int loff0 = (wid*64)*8;          // u16 offset of this wave's slot base, p=0
  const int loff1 = (256 + wid*64)*8;    // p=1

  f32x4 acc[4][4];
  #pragma unroll
  for (int m=0;m<4;++m)
    #pragma unroll
    for (int n=0;n<4;++n) acc[m][n] = (f32x4){0.f,0.f,0.f,0.f};

  const u16* Ap[2] = {A0, A1};
  const u16* Bp[2] = {B0, B1};

  for (int k0 = 0; k0 < Kp; k0 += 32){
    #pragma unroll
    for (int s=0;s<NS;++s){
      u16* al = &As[s][0][0];
      u16* bl = &Bs[s][0][0];
      gload16(Ap[s] + (size_t)(rowBase + srow[0])*Kp + (k0 + scol[0]*8), al + loff0);
      gload16(Ap[s] + (size_t)(rowBase + srow[1])*Kp + (k0 + scol[1]*8), al + loff1);
      gload16(Bp[s] + (size_t)(colBase + srow[0])*Kp + (k0 + scol[0]*8), bl + loff0);
      gload16(Bp[s] + (size_t)(colBase + srow[1])*Kp + (k0 + scol[1]*8), bl + loff1);
    }
    __syncthreads();
    V8 af[NS][4], bfr[NS][4];
    #pragma unroll
    for (int s=0;s<NS;++s)
      #pragma unroll
      for (int m=0;m<4;++m){
        int r = wr + m*16 + lrow;
        af[s][m].s = *(const short8*)(&As[s][0][0] + r*32 + ((lq ^ (r&3))<<3));
      }
    #pragma unroll
    for (int s=0;s<NS;++s)
      #pragma unroll
      for (int n=0;n<4;++n){
        int r = wc + n*16 + lrow;
        bfr[s][n].s = *(const short8*)(&Bs[s][0][0] + r*32 + ((lq ^ (r&3))<<3));
      }
    #pragma unroll
    for (int m=0;m<4;++m)
      #pragma unroll
      for (int n=0;n<4;++n){
        acc[m][n] = __builtin_amdgcn_mfma_f32_16x16x32_bf16(af[0][m].b, bfr[0][n].b, acc[m][n], 0,0,0);
        if (NS == 2){
          acc[m][n] = __builtin_amdgcn_mfma_f32_16x16x32_bf16(af[NS-1][m].b, bfr[0][n].b, acc[m][n], 0,0,0);
          acc[m][n] = __builtin_amdgcn_mfma_f32_16x16x32_bf16(af[0][m].b, bfr[NS-1][n].b, acc[m][n], 0,0,0);
        }
      }
    __syncthreads();
  }

  #pragma unroll
  for (int m=0;m<4;++m)
    #pragma unroll
    for (int n=0;n<4;++n)
      #pragma unroll
      for (int r=0;r<4;++r){
        int row = rowBase + wr + m*16 + lq*4 + r;
        int col = colBase + wc + n*16 + lrow;
        if (col < N){
          float c = acc[m][n][r];
          if (EPI == 3) c = sqf[row] + sqf[col] - 2.0f*c;
          if (bias) c += bias[col];
          if (EPI == 1) c = tanhf(c);
          if (EPI == 2) c = 1.0f/(1.0f + expf(-c));
          C[(size_t)row*N + col] = c;
        }
      }
}

// ---------------- f32 LDS-tiled GEMM (small hpre only) ----------------
template<int EPI>
__global__ __launch_bounds__(256) void sgemm_k(
    const float* __restrict__ A, const float* __restrict__ B,
    const float* __restrict__ bias, float* __restrict__ C, int M, int N, int K)
{
  __shared__ float As[64][17];
  __shared__ float Bs[16][65];
  const int tid = threadIdx.x;
  const int tx = tid & 15, ty = tid >> 4;
  const int rowBase = blockIdx.y*64, colBase = blockIdx.x*64;
  float acc[4][4] = {{0.f}};
  for (int k0 = 0; k0 < K; k0 += 16){
    #pragma unroll
    for (int p = 0; p < 4; ++p){
      int idx = p*256 + tid;
      int r = idx >> 4, kk = idx & 15;
      int gk = k0 + kk;
      As[r][kk] = (gk < K) ? A[(size_t)(rowBase+r)*K + gk] : 0.f;
    }
    #pragma unroll
    for (int p = 0; p < 4; ++p){
      int idx = p*256 + tid;
      int k = idx >> 6, c = idx & 63;
      int gk = k0 + k, gc = colBase + c;
      Bs[k][c] = (gk < K && gc < N) ? B[(size_t)gk*N + gc] : 0.f;
    }
    __syncthreads();
    #pragma unroll
    for (int k = 0; k < 16; ++k){
      float a[4], b[4];
      #pragma unroll
      for (int i=0;i<4;++i) a[i] = As[ty*4+i][k];
      #pragma unroll
      for (int j=0;j<4;++j) b[j] = Bs[k][tx*4+j];
      #pragma unroll
      for (int i=0;i<4;++i)
        #pragma unroll
        for (int j=0;j<4;++j) acc[i][j] = fmaf(a[i], b[j], acc[i][j]);
    }
    __syncthreads();
  }
  #pragma unroll
  for (int i=0;i<4;++i){
    int row = rowBase + ty*4 + i;
    #pragma unroll
    for (int j=0;j<4;++j){
      int col = colBase + tx*4 + j;
      if (col < N){
        float c = acc[i][j];
        if (bias) c += bias[col];
        if (EPI == 1) c = tanhf(c);
        C[(size_t)row*N + col] = c;
      }
    }
  }
}

// ---------------- kNN: f32 top-10 window + margin candidates (cap 96) ----------------
__global__ __launch_bounds__(256) void knn_select(const float* __restrict__ dists,
                                                  int* __restrict__ cand, int* __restrict__ candc){
  const int row = blockIdx.x, tid = threadIdx.x;
  __shared__ float drow[4096];
  __shared__ float rv[256]; __shared__ int ri[256];
  __shared__ float d10s;
  const float* dr = dists + (size_t)row*4096;
  for (int j = tid; j < 4096; j += 256) drow[j] = dr[j];
  __syncthreads();
  for (int t = 0; t < 10; ++t){
    float bv = 3.4e38f; int bi = 0x7FFFFFFF;
    for (int j = tid; j < 4096; j += 256){
      float v = drow[j];
      if (v < bv || (v == bv && j < bi)){ bv = v; bi = j; }
    }
    rv[tid] = bv; ri[tid] = bi;
    __syncthreads();
    for (int s = 128; s > 0; s >>= 1){
      if (tid < s){
        float ov = rv[tid+s]; int oi = ri[tid+s];
        if (ov < rv[tid] || (ov == rv[tid] && oi < ri[tid])){ rv[tid] = ov; ri[tid] = oi; }
      }
      __syncthreads();
    }
    if (tid == 0){ drow[ri[0]] = 3.4e38f; if (t == 9) d10s = rv[0]; }
    __syncthreads();
  }
  const float thr = d10s + 2.0f;
  if (tid < 64){
    int lane = tid;
    int cnt = 0;
    for (int base = 0; base < 4096; base += 64){
      bool p = dr[base+lane] <= thr;
      unsigned long long mask = __ballot(p);
      if (p){
        int pos = __popcll(mask & ((1ull<<lane)-1ull));
        if (cnt + pos < 96) cand[(size_t)row*96 + cnt + pos] = base + lane;
      }
      cnt += __popcll(mask);
    }
    if (lane == 0) candc[row] = cnt < 96 ? cnt : 96;
  }
}

// ---------------- kNN: f32-MIMIC re-rank ----------------
__global__ __launch_bounds__(256) void knn_rank32(const float* __restrict__ x,
    const int* __restrict__ cand, const int* __restrict__ candc,
    int* __restrict__ nbrK, int* __restrict__ nbrKc)
{
  const int row = blockIdx.x, tid = threadIdx.x;
  const int wid = tid>>6, lane = tid&63;
  __shared__ float xi[1024];
  __shared__ float cd[96];
  __shared__ float sqi_sh;
  const float* xr = x + (size_t)row*1024;
  for (int k = tid; k < 1024; k += 256) xi[k] = xr[k];
  __syncthreads();
  if (wid == 0){
    float a = 0.f;
    #pragma unroll
    for (int t = 0; t < 16; ++t){ float v = xi[lane + 64*t]; a = fmaf(v, v, a); }
    a += __shfl_xor(a, 16); a += __shfl_xor(a, 32);
    a += __shfl_xor(a, 8);  a += __shfl_xor(a, 4);
    a += __shfl_xor(a, 2);  a += __shfl_xor(a, 1);
    if (lane == 0) sqi_sh = a;
  }
  __syncthreads();
  const float sqi = sqi_sh;
  const int cnt = candc[row];
  for (int s = wid; s < cnt; s += 4){
    int c = cand[(size_t)row*96 + s];
    const float* xc = x + (size_t)c*1024;
    float ad = 0.f, aq = 0.f;
    #pragma unroll
    for (int t = 0; t < 16; ++t){
      int k = lane + 64*t;
      float v = xc[k];
      ad = fmaf(xi[k], v, ad);
      aq = fmaf(v, v, aq);
    }
    ad += __shfl_xor(ad, 16); ad += __shfl_xor(ad, 32);
    ad += __shfl_xor(ad, 8);  ad += __shfl_xor(ad, 4);
    ad += __shfl_xor(ad, 2);  ad += __shfl_xor(ad, 1);
    aq += __shfl_xor(aq, 16); aq += __shfl_xor(aq, 32);
    aq += __shfl_xor(aq, 8);  aq += __shfl_xor(aq, 4);
    aq += __shfl_xor(aq, 2);  aq += __shfl_xor(aq, 1);
    if (lane == 0) cd[s] = (sqi - 2.0f*ad) + aq;
  }
  __syncthreads();
  if (tid == 0){
    int m = 0;
    int lim = cnt < 10 ? cnt : 10;
    for (int t = 0; t < lim; ++t){
      float bd = 3.4e38f; int bs = 0;
      for (int s = 0; s < cnt; ++s){
        if (cd[s] < bd){ bd = cd[s]; bs = s; }
      }
      cd[bs] = 3.4e38f;
      int j = cand[(size_t)row*96 + bs];
      if (j != row && m < 10){ nbrK[row*10 + m] = j; ++m; }
    }
    nbrKc[row] = m;
  }
}

__global__ __launch_bounds__(64) void scatter_k(const int* __restrict__ nbrK, const int* __restrict__ nbrKc,
                                                float* __restrict__ g){
  int row = blockIdx.x, t = threadIdx.x;
  int m = nbrKc[row];
  if (t < m){
    int j = nbrK[row*10 + t];
    g[(size_t)row*4096 + j] = 1.0f;
    g[(size_t)j*4096 + row] = 1.0f;
  }
}

__global__ __launch_bounds__(64) void build_lists(const float* __restrict__ g, int* __restrict__ nbrl,
                                                  int* __restrict__ nbrc, float* __restrict__ dinv){
  int row = blockIdx.x, lane = threadIdx.x;
  const float* gr = g + (size_t)row*4096;
  int cnt = 0;
  for (int base = 0; base < 4096; base += 64){
    bool p = gr[base+lane] != 0.f;
    unsigned long long mask = __ballot(p);
    if (p){
      int pos = __popcll(mask & ((1ull<<lane)-1ull));
      if (cnt + pos < NBR_CAP) nbrl[(size_t)row*NBR_CAP + cnt + pos] = base + lane;
    }
    cnt += __popcll(mask);
  }
  if (lane == 0){
    nbrc[row] = cnt < NBR_CAP ? cnt : NBR_CAP;
    dinv[row] = 1.0f/sqrtf((float)(cnt + 1));
  }
}

// ---------------- SpMM v3: float4 per thread, 256 cols/block ----------------
__global__ __launch_bounds__(256) void spmm_k(const float* __restrict__ X, const int* __restrict__ nbrl,
    const int* __restrict__ nbrc, const float* __restrict__ dinv, float* __restrict__ out, int W){
  const int row = blockIdx.y;
  const int lane = threadIdx.x & 63;
  const int sl = threadIdx.x >> 6;
  const int col4 = blockIdx.x*256 + lane*4;
  __shared__ int li[NBR_CAP]; __shared__ float lv[NBR_CAP];
  __shared__ f32x4 red[4][64];
  const int cnt = nbrc[row];
  for (int t = threadIdx.x; t < cnt; t += 256){
    int j = nbrl[(size_t)row*NBR_CAP + t];
    li[t] = j; lv[t] = dinv[j];
  }
  __syncthreads();
  const float di = dinv[row];
  f32x4 p = {0.f,0.f,0.f,0.f};
  if (col4 + 3 < W){
    for (int s = sl; s < cnt; s += 4){
      f32x4 xv = *(const f32x4*)(X + (size_t)li[s]*W + col4);
      p += lv[s]*xv;
    }
    if (sl == 0){
      f32x4 xv = *(const f32x4*)(X + (size_t)row*W + col4);
      p += di*xv;
    }
  } else if (col4 < W){
    #pragma unroll
    for (int e = 0; e < 4; ++e){
      int c = col4 + e;
      if (c < W){
        float a = 0.f;
        for (int s = sl; s < cnt; s += 4) a = fmaf(lv[s], X[(size_t)li[s]*W + c], a);
        if (sl == 0) a = fmaf(di, X[(size_t)row*W + c], a);
        p[e] = a;
      }
    }
  }
  red[sl][lane] = p;
  __syncthreads();
  if (sl == 0 && col4 < W){
    f32x4 acc = red[0][lane] + red[1][lane] + red[2][lane] + red[3][lane];
    acc = di*acc;
    #pragma unroll
    for (int e = 0; e < 4; ++e){
      int c = col4 + e;
      if (c < W) out[(size_t)row*W + c] = acc[e];
    }
  }
}

// ---------------- q = softmax(z @ lc_w + lc_b) ----------------
__global__ __launch_bounds__(64) void q_kernel(const float* __restrict__ z, const float* __restrict__ lcw,
                                               const float* __restrict__ lcb, float* __restrict__ qs){
  int row = blockIdx.x, lane = threadIdx.x;
  __shared__ float ls[10];
  const float* zr = z + (size_t)row*512;
  for (int c = 0; c < 10; ++c){
    float a = 0.f;
    for (int k = lane; k < 512; k += 64) a += zr[k]*lcw[k*10 + c];
    for (int o = 32; o > 0; o >>= 1) a += __shfl_down(a, o);
    if (lane == 0) ls[c] = a + lcb[c];
  }
  __syncthreads();
  if (lane == 0){
    float m = ls[0];
    for (int c = 1; c < 10; ++c) m = fmaxf(m, ls[c]);
    float sum = 0.f, e[10];
    for (int c = 0; c < 10; ++c){ e[c] = expf(ls[c]-m); sum += e[c]; }
    for (int c = 0; c < 10; ++c) qs[(size_t)row*10 + c] = e[c]/sum;
  }
}

// ---------------- h row-normalize ----------------
__global__ __launch_bounds__(64) void hnorm_k(const float* __restrict__ hp, float* __restrict__ hs){
  int row = blockIdx.x, lane = threadIdx.x;
  const float* hr = hp + (size_t)row*128;
  float v0 = hr[lane], v1 = hr[lane+64];
  float a = v0*v0 + v1*v1;
  for (int o = 32; o > 0; o >>= 1) a += __shfl_down(a, o);
  float nrm = sqrtf(__shfl(a, 0));
  hs[(size_t)row*128 + lane]      = v0/nrm;
  hs[(size_t)row*128 + lane + 64] = v1/nrm;
}

extern "C" void kernel_launch(void* const* d_in, const int* in_sizes, int n_in,
                              void* d_out, int out_size, void* d_ws, size_t ws_size,
                              hipStream_t stream)
{
  const float* xs  = (const float*)d_in[0];
  const float* ew1 = (const float*)d_in[1];
  const float* eb1 = (const float*)d_in[2];
  const float* ew2 = (const float*)d_in[3];
  const float* eb2 = (const float*)d_in[4];
  const float* eWp = (const float*)d_in[5];
  const float* dW1 = (const float*)d_in[6];
  const float* dw1 = (const float*)d_in[7];
  const float* db1 = (const float*)d_in[8];
  const float* dw2 = (const float*)d_in[9];
  const float* db2 = (const float*)d_in[10];
  const float* fcw = (const float*)d_in[11];
  const float* fcb = (const float*)d_in[12];
  const float* lcw = (const float*)d_in[13];
  const float* lcb = (const float*)d_in[14];

  float* out = (float*)d_out;
  const size_t HS0 = 0;
  const size_t QS0 = HS0 + (size_t)2*4096*128;
  const size_t XR0 = QS0 + (size_t)2*4096*10;
  const size_t ZS0 = XR0 + (size_t)2*4096*1024;
  const size_t GS0 = ZS0 + (size_t)2*4096*512;
  const size_t AR0 = GS0 + (size_t)2*4096*4096;

  void* sp = nullptr;
  hipGetSymbolAddress(&sp, HIP_SYMBOL(g_scratch));
  if (!sp) return;
  char* ws = (char*)sp;

  // region 0..64MB: dists during graph phase; padded split buffers afterwards
  float* dists = (float*)(ws + 0);
  u16* GAH = (u16*)(ws + 0);           // 14.94MB (4096x1824)
  u16* GAL = (u16*)(ws + 14942208);
  u16* GWH = (u16*)(ws + 29884416);    // 4MB (max 1920x1024 / 1024x1824)
  u16* GWL = (u16*)(ws + 34078720);
  u16* ZH  = (u16*)(ws + 38273024);    // 4MB (4096x512)
  u16* ZL  = (u16*)(ws + 42467328);
  u16* WH  = (u16*)(ws + 46661632);
  u16* WL  = (u16*)(ws + 50855936);    // ends 55.05MB < 64MB

  float* o1    = (float*)(ws + 67108864);     // 29.5MB (h11 aliases; XH aliases pre-o1)
  u16* XH = (u16*)(ws + 67108864);            // 8MB (4096x1024) — dists operand
  float* so1   = (float*)(ws + 96600064);     // 29.5MB (sh11 aliases)
  float* sx    = (float*)(ws + 126091264);    // 16MB
  float* sh1   = (float*)(ws + 142868480);    // 8MB
  float* zw    = (float*)(ws + 151257088);    // 8MB
  float* h1    = (float*)(ws + 159645696);    // 8MB
  float* hpre  = (float*)(ws + 168034304);    // 2MB
  float* sqf   = (float*)(ws + 170164224);
  int* cand    = (int*)(ws + 170180608);
  int* candc   = (int*)(ws + 171753472);
  int* nbrK    = (int*)(ws + 171769856);
  int* nbrKc   = (int*)(ws + 171933696);
  int* nbrl    = (int*)(ws + 171950080);      // 32MB
  int* nbrc    = (int*)(ws + 205504512);
  float* dinv  = (float*)(ws + 205520896);
  float* h11   = o1;
  float* sh11  = so1;

  zero_k<<<2048,256,0,stream>>>((f32x4*)(out + GS0), (size_t)2*4096*4096/4);

  for (int v = 0; v < 2; ++v){
    const float* x    = xs  + (size_t)v*4096*1024;
    const float* w1   = ew1 + (size_t)v*1024*1800;
    const float* b1   = eb1 + (size_t)v*1800;
    const float* w2   = ew2 + (size_t)v*1800*512;
    const float* b2   = eb2 + (size_t)v*512;
    const float* We   = eWp + (size_t)v*512*512;
    const float* dWv  = dW1 + (size_t)v*512*512;
    const float* dw1v = dw1 + (size_t)v*512*1800;
    const float* db1v = db1 + (size_t)v*1800;
    const float* dw2v = dw2 + (size_t)v*1800*1024;
    const float* db2v = db2 + (size_t)v*1024;
    float* hs_o = out + HS0 + (size_t)v*4096*128;
    float* qs_o = out + QS0 + (size_t)v*4096*10;
    float* xr_o = out + XR0 + (size_t)v*4096*1024;
    float* zs_o = out + ZS0 + (size_t)v*4096*512;
    float* gs_o = out + GS0 + (size_t)v*4096*4096;
    float* ar_o = out + AR0 + (size_t)v*4096*4096;

    // ---- graph ----
    sq_kernel<<<1024,256,0,stream>>>(x, sqf);
    split_pad<<<dim3(4,4096),256,0,stream>>>(x, XH, nullptr, 1024, 1024);
    gemm_bt<1,3><<<dim3(32,32),256,0,stream>>>(XH,nullptr,XH,nullptr,nullptr,sqf,dists,4096,4096,1024);
    knn_select<<<4096,256,0,stream>>>(dists, cand, candc);
    knn_rank32<<<4096,256,0,stream>>>(x, cand, candc, nbrK, nbrKc);
    scatter_k<<<4096,64,0,stream>>>(nbrK, nbrKc, gs_o);
    build_lists<<<4096,64,0,stream>>>(gs_o, nbrl, nbrc, dinv);

    // ---- encoder ----
    spmm_k<<<dim3(4,4096),256,0,stream>>>(x, nbrl, nbrc, dinv, sx, 1024);
    split_pad<<<dim3(4,4096),256,0,stream>>>(sx, GAH, GAL, 1024, 1024);
    tsplit_pad<<<dim3(30,16),256,0,stream>>>(w1, GWH, GWL, 1024, 1800, 1024, 1920);
    gemm_bt<2,1><<<dim3(15,32),256,0,stream>>>(GAH,GAL,GWH,GWL,b1,nullptr,o1,4096,1800,1024);
    spmm_k<<<dim3(8,4096),256,0,stream>>>(o1, nbrl, nbrc, dinv, so1, 1800);
    split_pad<<<dim3(8,4096),256,0,stream>>>(so1, GAH, GAL, 1800, 1824);
    tsplit_pad<<<dim3(8,29),256,0,stream>>>(w2, GWH, GWL, 1800, 512, 1824, 512);
    gemm_bt<2,1><<<dim3(4,32),256,0,stream>>>(GAH,GAL,GWH,GWL,b2,nullptr,zs_o,4096,512,1824);

    // ---- a = sigmoid((z@eW)@z^T) ----
    split_pad<<<dim3(2,4096),256,0,stream>>>(zs_o, ZH, ZL, 512, 512);
    tsplit_pad<<<dim3(8,8),256,0,stream>>>(We, GWH, GWL, 512, 512, 512, 512);
    gemm_bt<2,0><<<dim3(4,32),256,0,stream>>>(ZH,ZL,GWH,GWL,nullptr,nullptr,zw,4096,512,512);
    split_pad<<<dim3(2,4096),256,0,stream>>>(zw, WH, WL, 512, 512);
    gemm_bt<2,2><<<dim3(32,32),256,0,stream>>>(WH,WL,ZH,ZL,nullptr,nullptr,ar_o,4096,4096,512);

    // ---- heads ----
    sgemm_k<0><<<dim3(2,64),256,0,stream>>>(zs_o,fcw,fcb,hpre,4096,128,512);
    hnorm_k<<<4096,64,0,stream>>>(hpre, hs_o);
    q_kernel<<<4096,64,0,stream>>>(zs_o, lcw, lcb, qs_o);

    // ---- decoder ----
    tsplit_pad<<<dim3(8,8),256,0,stream>>>(dWv, GWH, GWL, 512, 512, 512, 512);
    gemm_bt<2,1><<<dim3(4,32),256,0,stream>>>(ZH,ZL,GWH,GWL,nullptr,nullptr,h1,4096,512,512);
    spmm_k<<<dim3(2,4096),256,0,stream>>>(h1, nbrl, nbrc, dinv, sh1, 512);
    split_pad<<<dim3(2,4096),256,0,stream>>>(sh1, GAH, GAL, 512, 512);
    tsplit_pad<<<dim3(30,8),256,0,stream>>>(dw1v, GWH, GWL, 512, 1800, 512, 1920);
    gemm_bt<2,1><<<dim3(15,32),256,0,stream>>>(GAH,GAL,GWH,GWL,db1v,nullptr,h11,4096,1800,512);
    spmm_k<<<dim3(8,4096),256,0,stream>>>(h11, nbrl, nbrc, dinv, sh11, 1800);
    split_pad<<<dim3(8,4096),256,0,stream>>>(sh11, GAH, GAL, 1800, 1824);
    tsplit_pad<<<dim3(16,29),256,0,stream>>>(dw2v, GWH, GWL, 1800, 1024, 1824, 1024);
    gemm_bt<2,1><<<dim3(8,32),256,0,stream>>>(GAH,GAL,GWH,GWL,db2v,nullptr,xr_o,4096,1024,1824);
  }
}